// Round 1
// baseline (1192.274 us; speedup 1.0000x reference)
//
#include <hip/hip_runtime.h>
#include <hip/hip_bf16.h>

// ---------------- problem constants ----------------
#define Bb   2
#define Cc   256
#define Nn   1024
#define Mm   65536
#define MCn  8            // m-chunks for parallelism
#define VROWS 272         // 256 desc + 3 coords + 1 weight + 12 pad
#define MSTEP 32

// workspace byte offsets
#define SCL_OFF  0L                               // B*M f32           (0.5 MB)
#define TMC_OFF  524288L                          // B*M*C bf16        (67 MB)   K: [b][m][c]
#define TCM_OFF  67633152L                        // B*272*M bf16      (71.3 MB) V: [b][row][m]
#define SNC_OFF  138936320L                       // B*N*C bf16        (1 MB)    Q^T: [b][n][c]
#define PART_OFF 139984896L                       // B*MC*N*272 f32    (17.8 MB)
#define ZP_OFF   157810688L                       // B*MC*N f32
#define PP_OFF   157876224L                       // B*MC*N f32

// output float offsets
#define O_COORD 0L
#define O_W     6144L
#define O_DESC  8192L
#define O_P2D   532480L
#define O_VALID 536576L
#define O_MAXSM 538624L

using f32x4 = __attribute__((ext_vector_type(4))) float;
using s16x8 = __attribute__((ext_vector_type(8))) short;

__device__ inline unsigned short f2bf(float x) {
    union { float f; unsigned int u; } v; v.f = x;
    unsigned int r = v.u + 0x7FFFu + ((v.u >> 16) & 1u);   // RNE
    return (unsigned short)(r >> 16);
}

// ------- prep 1: per-column stats -> scl, plus vx rows of V (coords/weights) -------
__global__ void k_prep_stats(const float* __restrict__ tgt_desc,
                             const float* __restrict__ coords,
                             const float* __restrict__ weights,
                             float* __restrict__ scl,
                             unsigned short* __restrict__ tcm) {
    int b = blockIdx.y;
    long m = (long)blockIdx.x * 256 + threadIdx.x;
    const float* col = tgt_desc + (long)b * Cc * Mm + m;
    float s = 0.f, s2 = 0.f;
    for (int c = 0; c < Cc; ++c) { float v = col[(long)c * Mm]; s += v; s2 += v * v; }
    float var = fmaxf((s2 - s * s * (1.0f / Cc)) * (1.0f / (Cc - 1)), 1e-20f);
    // fold: 1/std * 1/(C*TEMP) * log2(e)
    scl[(long)b * Mm + m] = 1.4426950408889634f * rsqrtf(var) * (1.0f / (Cc * 0.01f));
    unsigned short* vrow = tcm + ((long)b * VROWS + 256) * Mm + m;
    #pragma unroll
    for (int i = 0; i < 3; ++i) vrow[(long)i * Mm] = f2bf(coords[((long)b * 3 + i) * Mm + m]);
    vrow[3L * Mm] = f2bf(weights[(long)b * Mm + m]);
    #pragma unroll
    for (int i = 4; i < 16; ++i) vrow[(long)i * Mm] = 0;
}

// ------- prep 2: tgt_desc f32 (c-major) -> tmc bf16 [b][m][c] (transposed) + tcm bf16 [b][c][m] -------
__global__ void k_prep_tgt(const float* __restrict__ tgt,
                           unsigned short* __restrict__ tmc,
                           unsigned short* __restrict__ tcm) {
    __shared__ float lds[64][65];
    int b = blockIdx.z, c0 = blockIdx.y * 64;
    long m0 = (long)blockIdx.x * 64;
    int ty = threadIdx.x >> 6, tx = threadIdx.x & 63;
    #pragma unroll
    for (int k = 0; k < 16; ++k) {
        int ci = 4 * k + ty;
        float v = tgt[((long)b * Cc + c0 + ci) * Mm + m0 + tx];
        lds[ci][tx] = v;
        tcm[((long)b * VROWS + c0 + ci) * Mm + m0 + tx] = f2bf(v);
    }
    __syncthreads();
    #pragma unroll
    for (int k = 0; k < 16; ++k) {
        int mi = 4 * k + ty;
        tmc[((long)b * Mm + m0 + mi) * Cc + c0 + tx] = f2bf(lds[tx][mi]);
    }
}

// ------- prep 3: src_desc_norm f32 (c-major) -> snc bf16 [b][n][c] -------
__global__ void k_prep_src(const float* __restrict__ src, unsigned short* __restrict__ snc) {
    __shared__ float lds[64][65];
    int b = blockIdx.z, c0 = blockIdx.y * 64, n0 = blockIdx.x * 64;
    int ty = threadIdx.x >> 6, tx = threadIdx.x & 63;
    #pragma unroll
    for (int k = 0; k < 16; ++k)
        lds[4 * k + ty][tx] = src[((long)b * Cc + c0 + 4 * k + ty) * Nn + n0 + tx];
    __syncthreads();
    #pragma unroll
    for (int k = 0; k < 16; ++k) {
        int ni = 4 * k + ty;
        snc[((long)b * Nn + n0 + ni) * Cc + c0 + tx] = f2bf(lds[tx][ni]);
    }
}

// ------- main fused kernel: S^T = K·Q^T (MFMA), p = 2^(S*scl), out^T += V^T·P^T -------
__global__ __launch_bounds__(256) void k_main(const unsigned short* __restrict__ tmc,
                                              const unsigned short* __restrict__ tcm,
                                              const unsigned short* __restrict__ snc,
                                              const float* __restrict__ scl,
                                              float* __restrict__ part,
                                              float* __restrict__ zp,
                                              float* __restrict__ pp) {
    __shared__ __align__(16) unsigned short pbuf[4][16][32];
    int w = threadIdx.x >> 6, lane = threadIdx.x & 63;
    int l15 = lane & 15, lg = lane >> 4;
    int b = blockIdx.z, nt = blockIdx.y, mc = blockIdx.x;
    int nb = nt * 64 + w * 16;

    // Q^T B-fragments: lane holds Q[n=l15][c = cc*32 + lg*8 .. +7]
    const unsigned short* qp = snc + ((long)b * Nn + nb + l15) * Cc + lg * 8;
    s16x8 qf[8];
    #pragma unroll
    for (int cc = 0; cc < 8; ++cc) qf[cc] = *(const s16x8*)(qp + cc * 32);

    f32x4 acc[17];
    #pragma unroll
    for (int t = 0; t < 17; ++t) acc[t] = (f32x4){0.f, 0.f, 0.f, 0.f};
    float zacc = 0.f, pmax = 0.f;

    long mbase = (long)mc * (Mm / MCn);
    const float* sclb = scl + (long)b * Mm;

    for (int s = 0; s < (Mm / MCn) / MSTEP; ++s) {
        long m0 = mbase + (long)s * MSTEP;
        const unsigned short* kp = tmc + ((long)b * Mm + m0 + l15) * Cc + lg * 8;
        // two 16-m subtiles
        #pragma unroll
        for (int t = 0; t < 2; ++t) {
            f32x4 d = (f32x4){0.f, 0.f, 0.f, 0.f};
            #pragma unroll
            for (int cc = 0; cc < 8; ++cc) {
                s16x8 kf = *(const s16x8*)(kp + (long)t * 16 * Cc + cc * 32);
                d = __builtin_amdgcn_mfma_f32_16x16x32_bf16(kf, qf[cc], d, 0, 0, 0);
            }
            // d[r] = S0 for (m = m0 + t*16 + lg*4 + r, n = nb + l15)
            float4 sc = *(const float4*)(sclb + m0 + t * 16 + lg * 4);
            float p0 = exp2f(d.x * sc.x);
            float p1 = exp2f(d.y * sc.y);
            float p2 = exp2f(d.z * sc.z);
            float p3 = exp2f(d.w * sc.w);
            zacc += (p0 + p1) + (p2 + p3);
            pmax = fmaxf(pmax, fmaxf(fmaxf(p0, p1), fmaxf(p2, p3)));
            unsigned int lo = (unsigned)f2bf(p0) | ((unsigned)f2bf(p1) << 16);
            unsigned int hi = (unsigned)f2bf(p2) | ((unsigned)f2bf(p3) << 16);
            unsigned int* dst = (unsigned int*)&pbuf[w][l15][t * 16 + lg * 4];
            dst[0] = lo; dst[1] = hi;
        }
        asm volatile("s_waitcnt lgkmcnt(0)" ::: "memory");
        __builtin_amdgcn_sched_barrier(0);
        // P^T B-fragment: lane holds P[n=l15][m-in-32 = lg*8 .. +7]
        s16x8 pf = *(const s16x8*)&pbuf[w][l15][lg * 8];
        // PV: out^T tile (16 c-rows x 16 n), A = V^T from tcm (contiguous m)
        #pragma unroll
        for (int t = 0; t < 17; ++t) {
            const unsigned short* vpt = tcm + ((long)b * VROWS + t * 16 + l15) * Mm + m0 + lg * 8;
            s16x8 vf = *(const s16x8*)vpt;
            acc[t] = __builtin_amdgcn_mfma_f32_16x16x32_bf16(vf, pf, acc[t], 0, 0, 0);
        }
    }

    // reduce Z / pmax across the 4 lane-groups (rows of m are split over lg)
    float zt = zacc + __shfl_xor(zacc, 16); zt = zt + __shfl_xor(zt, 32);
    float pt = fmaxf(pmax, __shfl_xor(pmax, 16)); pt = fmaxf(pt, __shfl_xor(pt, 32));
    if (lane < 16) {
        long zi = ((long)(b * MCn + mc)) * Nn + nb + lane;
        zp[zi] = zt;
        pp[zi] = pt;
    }
    // partial channel sums: channel c = t*16 + lg*4 + r for n = nb + l15
    float* po = part + (((long)(b * MCn + mc) * Nn) + nb + l15) * VROWS;
    #pragma unroll
    for (int t = 0; t < 17; ++t) {
        po[t * 16 + lg * 4 + 0] = acc[t].x;
        po[t * 16 + lg * 4 + 1] = acc[t].y;
        po[t * 16 + lg * 4 + 2] = acc[t].z;
        po[t * 16 + lg * 4 + 3] = acc[t].w;
    }
}

// ------- epilogue: combine m-chunks, normalize, zn(descs), 2D projection, max_softmax -------
__global__ void k_epi(const float* __restrict__ part,
                      const float* __restrict__ zp,
                      const float* __restrict__ pp,
                      float* __restrict__ out) {
    int w = threadIdx.x >> 6, lane = threadIdx.x & 63;
    int bn = blockIdx.x * 4 + w;
    int b = bn >> 10, n = bn & 1023;

    float Z = 0.f, pm = 0.f;
    #pragma unroll
    for (int mc = 0; mc < MCn; ++mc) {
        long zi = ((long)(b * MCn + mc)) * Nn + n;
        Z += zp[zi];
        pm = fmaxf(pm, pp[zi]);
    }
    float invZ = 1.0f / Z;

    float dv[4], s1 = 0.f, s2 = 0.f;
    #pragma unroll
    for (int k = 0; k < 4; ++k) {
        int c = lane + 64 * k;
        float s = 0.f;
        #pragma unroll
        for (int mc = 0; mc < MCn; ++mc)
            s += part[((long)(b * MCn + mc) * Nn + n) * VROWS + c];
        float d = s * invZ;
        dv[k] = d; s1 += d; s2 += d * d;
    }
    #pragma unroll
    for (int off = 1; off < 64; off <<= 1) { s1 += __shfl_xor(s1, off); s2 += __shfl_xor(s2, off); }
    float mean = s1 * (1.0f / 256.0f);
    float var = fmaxf((s2 - 256.0f * mean * mean) * (1.0f / 255.0f), 1e-20f);
    float istd = 1.0f / sqrtf(var);
    #pragma unroll
    for (int k = 0; k < 4; ++k)
        out[O_DESC + ((long)b * Cc + lane + 64 * k) * Nn + n] = (dv[k] - mean) * istd;

    float ex = 0.f;
    if (lane < 4) {
        int c = 256 + lane;
        #pragma unroll
        for (int mc = 0; mc < MCn; ++mc)
            ex += part[((long)(b * MCn + mc) * Nn + n) * VROWS + c];
        ex *= invZ;
    }
    float pc0 = __shfl(ex, 0), pc1 = __shfl(ex, 1), pc2 = __shfl(ex, 2), wv = __shfl(ex, 3);
    if (lane == 0) {
        out[O_COORD + ((long)b * 3 + 0) * Nn + n] = pc0;
        out[O_COORD + ((long)b * 3 + 1) * Nn + n] = pc1;
        out[O_COORD + ((long)b * 3 + 2) * Nn + n] = pc2;
        out[O_W + (long)b * Nn + n] = wv;
        const float cmin = 33.048f;                 // (256/2 - 0.5) * 0.2592
        out[O_P2D + ((long)b * Nn + n) * 2 + 0] = (cmin + pc1) * (1.0f / 0.2592f);
        out[O_P2D + ((long)b * Nn + n) * 2 + 1] = (cmin - pc0) * (1.0f / 0.2592f);
        out[O_VALID + (long)b * Nn + n] = 1.0f;
        atomicMax((unsigned int*)out + O_MAXSM + b, __float_as_uint(pm * invZ));
    }
}

extern "C" void kernel_launch(void* const* d_in, const int* in_sizes, int n_in,
                              void* d_out, int out_size, void* d_ws, size_t ws_size,
                              hipStream_t stream) {
    const float* tgt_coords  = (const float*)d_in[1];
    const float* tgt_weights = (const float*)d_in[3];
    const float* src_desc    = (const float*)d_in[5];
    const float* tgt_desc    = (const float*)d_in[6];

    char* ws = (char*)d_ws;
    float* scl           = (float*)(ws + SCL_OFF);
    unsigned short* tmc  = (unsigned short*)(ws + TMC_OFF);
    unsigned short* tcm  = (unsigned short*)(ws + TCM_OFF);
    unsigned short* snc  = (unsigned short*)(ws + SNC_OFF);
    float* part          = (float*)(ws + PART_OFF);
    float* zp            = (float*)(ws + ZP_OFF);
    float* pp            = (float*)(ws + PP_OFF);
    float* out           = (float*)d_out;

    k_prep_stats<<<dim3(Mm / 256, Bb), 256, 0, stream>>>(tgt_desc, tgt_coords, tgt_weights, scl, tcm);
    k_prep_tgt<<<dim3(Mm / 64, Cc / 64, Bb), 256, 0, stream>>>(tgt_desc, tmc, tcm);
    k_prep_src<<<dim3(Nn / 64, Cc / 64, Bb), 256, 0, stream>>>(src_desc, snc);
    k_main<<<dim3(MCn, Nn / 64, Bb), 256, 0, stream>>>(tmc, tcm, snc, scl, part, zp, pp);
    hipMemsetAsync((char*)d_out + O_MAXSM * 4, 0, 2 * sizeof(float), stream);
    k_epi<<<dim3((Bb * Nn) / 4), 256, 0, stream>>>(part, zp, pp, out);
}

// Round 2
// 1051.089 us; speedup vs baseline: 1.1343x; 1.1343x over previous
//
#include <hip/hip_runtime.h>
#include <hip/hip_bf16.h>

// ---------------- problem constants ----------------
#define Bb   2
#define Cc   256
#define Nn   1024
#define Mm   65536
#define MCn  8            // m-chunks (global partials) ; x4 waves in-block = 32-way m-split
#define VROWS 272         // 256 desc + 3 coords + 1 weight + 12 pad
#define VRP  276          // padded LDS row stride (floats)
#define MSTEP 32

// workspace byte offsets
#define SCL_OFF  0L                               // B*M f32           (0.5 MB)
#define TMC_OFF  524288L                          // B*M*C bf16        (67 MB)   K: [b][m][c]
#define TCM_OFF  67633152L                        // B*272*M bf16      (71.3 MB) V: [b][row][m]
#define SNC_OFF  138936320L                       // B*N*C bf16        (1 MB)    Q^T: [b][n][c]
#define PART_OFF 139984896L                       // B*MC*N*272 f32    (17.8 MB)
#define ZP_OFF   157810688L                       // B*MC*N f32
#define PP_OFF   157876224L                       // B*MC*N f32

// output float offsets
#define O_COORD 0L
#define O_W     6144L
#define O_DESC  8192L
#define O_P2D   532480L
#define O_VALID 536576L
#define O_MAXSM 538624L

using f32x4 = __attribute__((ext_vector_type(4))) float;
using s16x8 = __attribute__((ext_vector_type(8))) short;

__device__ inline unsigned short f2bf(float x) {
    union { float f; unsigned int u; } v; v.f = x;
    unsigned int r = v.u + 0x7FFFu + ((v.u >> 16) & 1u);   // RNE
    return (unsigned short)(r >> 16);
}

// ------- prep 1: per-column stats -> scl, plus vx rows of V (coords/weights) -------
__global__ void k_prep_stats(const float* __restrict__ tgt_desc,
                             const float* __restrict__ coords,
                             const float* __restrict__ weights,
                             float* __restrict__ scl,
                             unsigned short* __restrict__ tcm) {
    int b = blockIdx.y;
    long m = (long)blockIdx.x * 256 + threadIdx.x;
    const float* col = tgt_desc + (long)b * Cc * Mm + m;
    float s = 0.f, s2 = 0.f;
    for (int c = 0; c < Cc; ++c) { float v = col[(long)c * Mm]; s += v; s2 += v * v; }
    float var = fmaxf((s2 - s * s * (1.0f / Cc)) * (1.0f / (Cc - 1)), 1e-20f);
    // fold: 1/std * 1/(C*TEMP) * log2(e)
    scl[(long)b * Mm + m] = 1.4426950408889634f * rsqrtf(var) * (1.0f / (Cc * 0.01f));
    unsigned short* vrow = tcm + ((long)b * VROWS + 256) * Mm + m;
    #pragma unroll
    for (int i = 0; i < 3; ++i) vrow[(long)i * Mm] = f2bf(coords[((long)b * 3 + i) * Mm + m]);
    vrow[3L * Mm] = f2bf(weights[(long)b * Mm + m]);
    #pragma unroll
    for (int i = 4; i < 16; ++i) vrow[(long)i * Mm] = 0;
}

// ------- prep 2: tgt_desc f32 (c-major) -> tmc bf16 [b][m][c] (transposed) + tcm bf16 [b][c][m] -------
__global__ void k_prep_tgt(const float* __restrict__ tgt,
                           unsigned short* __restrict__ tmc,
                           unsigned short* __restrict__ tcm) {
    __shared__ float lds[64][65];
    int b = blockIdx.z, c0 = blockIdx.y * 64;
    long m0 = (long)blockIdx.x * 64;
    int ty = threadIdx.x >> 6, tx = threadIdx.x & 63;
    #pragma unroll
    for (int k = 0; k < 16; ++k) {
        int ci = 4 * k + ty;
        float v = tgt[((long)b * Cc + c0 + ci) * Mm + m0 + tx];
        lds[ci][tx] = v;
        tcm[((long)b * VROWS + c0 + ci) * Mm + m0 + tx] = f2bf(v);
    }
    __syncthreads();
    #pragma unroll
    for (int k = 0; k < 16; ++k) {
        int mi = 4 * k + ty;
        tmc[((long)b * Mm + m0 + mi) * Cc + c0 + tx] = f2bf(lds[tx][mi]);
    }
}

// ------- prep 3: src_desc_norm f32 (c-major) -> snc bf16 [b][n][c] -------
__global__ void k_prep_src(const float* __restrict__ src, unsigned short* __restrict__ snc) {
    __shared__ float lds[64][65];
    int b = blockIdx.z, c0 = blockIdx.y * 64, n0 = blockIdx.x * 64;
    int ty = threadIdx.x >> 6, tx = threadIdx.x & 63;
    #pragma unroll
    for (int k = 0; k < 16; ++k)
        lds[4 * k + ty][tx] = src[((long)b * Cc + c0 + 4 * k + ty) * Nn + n0 + tx];
    __syncthreads();
    #pragma unroll
    for (int k = 0; k < 16; ++k) {
        int ni = 4 * k + ty;
        snc[((long)b * Nn + n0 + ni) * Cc + c0 + tx] = f2bf(lds[tx][ni]);
    }
}

// ------- main fused kernel: S^T = K·Q^T (MFMA), p = 2^(S*scl), out^T += V^T·P^T -------
// block = 4 waves, all on the SAME 16-n tile; each wave owns a 2048-m sub-chunk.
// Per-wave partials are combined in LDS at the end (3 barriers), so the global
// `part` buffer keeps MCn=8 chunks and ws stays unchanged.
__global__ __launch_bounds__(256) void k_main(const unsigned short* __restrict__ tmc,
                                              const unsigned short* __restrict__ tcm,
                                              const unsigned short* __restrict__ snc,
                                              const float* __restrict__ scl,
                                              float* __restrict__ part,
                                              float* __restrict__ zp,
                                              float* __restrict__ pp) {
    __shared__ __align__(16) unsigned short pbuf[4][16][32];   // 4 KB, per-wave private
    __shared__ __align__(16) float red[16][VRP];               // 17.7 KB cross-wave reduce
    __shared__ float zs[4][16], ps[4][16];
    int w = threadIdx.x >> 6, lane = threadIdx.x & 63;
    int l15 = lane & 15, lg = lane >> 4;
    int b = blockIdx.z, nt = blockIdx.y, mc = blockIdx.x;
    int nb = nt * 16;

    // Q^T B-fragments: lane holds Q[n=l15][c = cc*32 + lg*8 .. +7] (same for all waves)
    const unsigned short* qp = snc + ((long)b * Nn + nb + l15) * Cc + lg * 8;
    s16x8 qf[8];
    #pragma unroll
    for (int cc = 0; cc < 8; ++cc) qf[cc] = *(const s16x8*)(qp + cc * 32);

    f32x4 acc[17];
    #pragma unroll
    for (int t = 0; t < 17; ++t) acc[t] = (f32x4){0.f, 0.f, 0.f, 0.f};
    float zacc = 0.f, pmax = 0.f;

    long mbase = (long)mc * (Mm / MCn) + (long)w * (Mm / MCn / 4);
    const float* sclb = scl + (long)b * Mm;

    for (int s = 0; s < (Mm / MCn / 4) / MSTEP; ++s) {
        long m0 = mbase + (long)s * MSTEP;
        const unsigned short* kp = tmc + ((long)b * Mm + m0 + l15) * Cc + lg * 8;
        // two 16-m subtiles
        #pragma unroll
        for (int t = 0; t < 2; ++t) {
            f32x4 d = (f32x4){0.f, 0.f, 0.f, 0.f};
            #pragma unroll
            for (int cc = 0; cc < 8; ++cc) {
                s16x8 kf = *(const s16x8*)(kp + (long)t * 16 * Cc + cc * 32);
                d = __builtin_amdgcn_mfma_f32_16x16x32_bf16(kf, qf[cc], d, 0, 0, 0);
            }
            // d[r] = S0 for (m = m0 + t*16 + lg*4 + r, n = nb + l15)
            float4 sc = *(const float4*)(sclb + m0 + t * 16 + lg * 4);
            float p0 = exp2f(d.x * sc.x);
            float p1 = exp2f(d.y * sc.y);
            float p2 = exp2f(d.z * sc.z);
            float p3 = exp2f(d.w * sc.w);
            zacc += (p0 + p1) + (p2 + p3);
            pmax = fmaxf(pmax, fmaxf(fmaxf(p0, p1), fmaxf(p2, p3)));
            unsigned int lo = (unsigned)f2bf(p0) | ((unsigned)f2bf(p1) << 16);
            unsigned int hi = (unsigned)f2bf(p2) | ((unsigned)f2bf(p3) << 16);
            unsigned int* dst = (unsigned int*)&pbuf[w][l15][t * 16 + lg * 4];
            dst[0] = lo; dst[1] = hi;
        }
        asm volatile("s_waitcnt lgkmcnt(0)" ::: "memory");
        __builtin_amdgcn_sched_barrier(0);
        // P^T B-fragment: lane holds P[n=l15][m-in-32 = lg*8 .. +7]
        s16x8 pf = *(const s16x8*)&pbuf[w][l15][lg * 8];
        // PV: out^T tile (16 c-rows x 16 n), A = V^T from tcm (contiguous m)
        #pragma unroll
        for (int t = 0; t < 17; ++t) {
            const unsigned short* vpt = tcm + ((long)b * VROWS + t * 16 + l15) * Mm + m0 + lg * 8;
            s16x8 vf = *(const s16x8*)vpt;
            acc[t] = __builtin_amdgcn_mfma_f32_16x16x32_bf16(vf, pf, acc[t], 0, 0, 0);
        }
    }

    // per-wave reduce Z / pmax across the 4 lane-groups
    float zt = zacc + __shfl_xor(zacc, 16); zt = zt + __shfl_xor(zt, 32);
    float pt = fmaxf(pmax, __shfl_xor(pmax, 16)); pt = fmaxf(pt, __shfl_xor(pt, 32));
    if (lane < 16) { zs[w][lane] = zt; ps[w][lane] = pt; }

    // cross-wave accumulate: sequential LDS RMW chain
    if (w == 0) {
        #pragma unroll
        for (int t = 0; t < 17; ++t)
            *(f32x4*)&red[l15][t * 16 + lg * 4] = acc[t];
    }
    __syncthreads();
    if (w == 1) {
        #pragma unroll
        for (int t = 0; t < 17; ++t) {
            f32x4* r = (f32x4*)&red[l15][t * 16 + lg * 4];
            *r = *r + acc[t];
        }
    }
    __syncthreads();
    if (w == 2) {
        #pragma unroll
        for (int t = 0; t < 17; ++t) {
            f32x4* r = (f32x4*)&red[l15][t * 16 + lg * 4];
            *r = *r + acc[t];
        }
    }
    __syncthreads();
    if (w == 3) {
        float* po = part + (((long)(b * MCn + mc) * Nn) + nb + l15) * VROWS;
        #pragma unroll
        for (int t = 0; t < 17; ++t) {
            f32x4 r = *(f32x4*)&red[l15][t * 16 + lg * 4] + acc[t];
            *(f32x4*)&po[t * 16 + lg * 4] = r;
        }
        if (lane < 16) {
            long zi = ((long)(b * MCn + mc)) * Nn + nb + lane;
            float Z = (zs[0][lane] + zs[1][lane]) + (zs[2][lane] + zs[3][lane]);
            float P = fmaxf(fmaxf(ps[0][lane], ps[1][lane]), fmaxf(ps[2][lane], ps[3][lane]));
            zp[zi] = Z;
            pp[zi] = P;
        }
    }
}

// ------- epilogue: combine m-chunks, normalize, zn(descs), 2D projection, max_softmax -------
__global__ void k_epi(const float* __restrict__ part,
                      const float* __restrict__ zp,
                      const float* __restrict__ pp,
                      float* __restrict__ out) {
    int w = threadIdx.x >> 6, lane = threadIdx.x & 63;
    int bn = blockIdx.x * 4 + w;
    int b = bn >> 10, n = bn & 1023;

    float Z = 0.f, pm = 0.f;
    #pragma unroll
    for (int mc = 0; mc < MCn; ++mc) {
        long zi = ((long)(b * MCn + mc)) * Nn + n;
        Z += zp[zi];
        pm = fmaxf(pm, pp[zi]);
    }
    float invZ = 1.0f / Z;

    float dv[4], s1 = 0.f, s2 = 0.f;
    #pragma unroll
    for (int k = 0; k < 4; ++k) {
        int c = lane + 64 * k;
        float s = 0.f;
        #pragma unroll
        for (int mc = 0; mc < MCn; ++mc)
            s += part[((long)(b * MCn + mc) * Nn + n) * VROWS + c];
        float d = s * invZ;
        dv[k] = d; s1 += d; s2 += d * d;
    }
    #pragma unroll
    for (int off = 1; off < 64; off <<= 1) { s1 += __shfl_xor(s1, off); s2 += __shfl_xor(s2, off); }
    float mean = s1 * (1.0f / 256.0f);
    float var = fmaxf((s2 - 256.0f * mean * mean) * (1.0f / 255.0f), 1e-20f);
    float istd = 1.0f / sqrtf(var);
    #pragma unroll
    for (int k = 0; k < 4; ++k)
        out[O_DESC + ((long)b * Cc + lane + 64 * k) * Nn + n] = (dv[k] - mean) * istd;

    float ex = 0.f;
    if (lane < 4) {
        int c = 256 + lane;
        #pragma unroll
        for (int mc = 0; mc < MCn; ++mc)
            ex += part[((long)(b * MCn + mc) * Nn + n) * VROWS + c];
        ex *= invZ;
    }
    float pc0 = __shfl(ex, 0), pc1 = __shfl(ex, 1), pc2 = __shfl(ex, 2), wv = __shfl(ex, 3);
    if (lane == 0) {
        out[O_COORD + ((long)b * 3 + 0) * Nn + n] = pc0;
        out[O_COORD + ((long)b * 3 + 1) * Nn + n] = pc1;
        out[O_COORD + ((long)b * 3 + 2) * Nn + n] = pc2;
        out[O_W + (long)b * Nn + n] = wv;
        const float cmin = 33.048f;                 // (256/2 - 0.5) * 0.2592
        out[O_P2D + ((long)b * Nn + n) * 2 + 0] = (cmin + pc1) * (1.0f / 0.2592f);
        out[O_P2D + ((long)b * Nn + n) * 2 + 1] = (cmin - pc0) * (1.0f / 0.2592f);
        out[O_VALID + (long)b * Nn + n] = 1.0f;
        atomicMax((unsigned int*)out + O_MAXSM + b, __float_as_uint(pm * invZ));
    }
}

extern "C" void kernel_launch(void* const* d_in, const int* in_sizes, int n_in,
                              void* d_out, int out_size, void* d_ws, size_t ws_size,
                              hipStream_t stream) {
    const float* tgt_coords  = (const float*)d_in[1];
    const float* tgt_weights = (const float*)d_in[3];
    const float* src_desc    = (const float*)d_in[5];
    const float* tgt_desc    = (const float*)d_in[6];

    char* ws = (char*)d_ws;
    float* scl           = (float*)(ws + SCL_OFF);
    unsigned short* tmc  = (unsigned short*)(ws + TMC_OFF);
    unsigned short* tcm  = (unsigned short*)(ws + TCM_OFF);
    unsigned short* snc  = (unsigned short*)(ws + SNC_OFF);
    float* part          = (float*)(ws + PART_OFF);
    float* zp            = (float*)(ws + ZP_OFF);
    float* pp            = (float*)(ws + PP_OFF);
    float* out           = (float*)d_out;

    k_prep_stats<<<dim3(Mm / 256, Bb), 256, 0, stream>>>(tgt_desc, tgt_coords, tgt_weights, scl, tcm);
    k_prep_tgt<<<dim3(Mm / 64, Cc / 64, Bb), 256, 0, stream>>>(tgt_desc, tmc, tcm);
    k_prep_src<<<dim3(Nn / 64, Cc / 64, Bb), 256, 0, stream>>>(src_desc, snc);
    k_main<<<dim3(MCn, Nn / 16, Bb), 256, 0, stream>>>(tmc, tcm, snc, scl, part, zp, pp);
    hipMemsetAsync((char*)d_out + O_MAXSM * 4, 0, 2 * sizeof(float), stream);
    k_epi<<<dim3((Bb * Nn) / 4), 256, 0, stream>>>(part, zp, pp, out);
}

// Round 3
// 541.927 us; speedup vs baseline: 2.2001x; 1.9395x over previous
//
#include <hip/hip_runtime.h>
#include <hip/hip_bf16.h>

// ---------------- problem constants ----------------
#define Bb   2
#define Cc   256
#define Nn   1024
#define Mm   65536
#define MCn  8            // m-chunks (global partials)
#define VROWS 272         // 256 desc + 3 coords + 1 weight + 12 pad
#define MSTEP 32
#define NIT  ((Mm / MCn) / MSTEP)   // 256 K-steps per block

// workspace byte offsets
#define SCL_OFF  0L                               // B*M f32           (0.5 MB)
#define TMC_OFF  524288L                          // B*M*C bf16        (67 MB)   K: [b][m][c]
#define TCM_OFF  67633152L                        // B*272*M bf16      (71.3 MB) V: [b][row][m]
#define SNC_OFF  138936320L                       // B*N*C bf16        (1 MB)    Q^T: [b][n][c]
#define PART_OFF 139984896L                       // B*MC*N*272 f32    (17.8 MB)
#define ZP_OFF   157810688L                       // B*MC*N f32
#define PP_OFF   157876224L                       // B*MC*N f32

// output float offsets
#define O_COORD 0L
#define O_W     6144L
#define O_DESC  8192L
#define O_P2D   532480L
#define O_VALID 536576L
#define O_MAXSM 538624L

using f32x4 = __attribute__((ext_vector_type(4))) float;
using s16x8 = __attribute__((ext_vector_type(8))) short;

__device__ inline unsigned short f2bf(float x) {
    union { float f; unsigned int u; } v; v.f = x;
    unsigned int r = v.u + 0x7FFFu + ((v.u >> 16) & 1u);   // RNE
    return (unsigned short)(r >> 16);
}

__device__ inline void gld_lds16(const unsigned short* g, unsigned short* l) {
    __builtin_amdgcn_global_load_lds(
        (const __attribute__((address_space(1))) unsigned int*)g,
        (__attribute__((address_space(3))) unsigned int*)l, 16, 0, 0);
}

// ------- prep 1: per-column stats -> scl, plus extra rows of V (coords/weights) -------
__global__ void k_prep_stats(const float* __restrict__ tgt_desc,
                             const float* __restrict__ coords,
                             const float* __restrict__ weights,
                             float* __restrict__ scl,
                             unsigned short* __restrict__ tcm) {
    int b = blockIdx.y;
    long m = (long)blockIdx.x * 256 + threadIdx.x;
    const float* col = tgt_desc + (long)b * Cc * Mm + m;
    float s = 0.f, s2 = 0.f;
    for (int c = 0; c < Cc; ++c) { float v = col[(long)c * Mm]; s += v; s2 += v * v; }
    float var = fmaxf((s2 - s * s * (1.0f / Cc)) * (1.0f / (Cc - 1)), 1e-20f);
    scl[(long)b * Mm + m] = 1.4426950408889634f * rsqrtf(var) * (1.0f / (Cc * 0.01f));
    unsigned short* vrow = tcm + ((long)b * VROWS + 256) * Mm + m;
    #pragma unroll
    for (int i = 0; i < 3; ++i) vrow[(long)i * Mm] = f2bf(coords[((long)b * 3 + i) * Mm + m]);
    vrow[3L * Mm] = f2bf(weights[(long)b * Mm + m]);
    #pragma unroll
    for (int i = 4; i < 16; ++i) vrow[(long)i * Mm] = 0;
}

// ------- prep 2: tgt_desc f32 -> tmc bf16 [b][m][c] + tcm bf16 [b][c][m] -------
__global__ void k_prep_tgt(const float* __restrict__ tgt,
                           unsigned short* __restrict__ tmc,
                           unsigned short* __restrict__ tcm) {
    __shared__ float lds[64][65];
    int b = blockIdx.z, c0 = blockIdx.y * 64;
    long m0 = (long)blockIdx.x * 64;
    int ty = threadIdx.x >> 6, tx = threadIdx.x & 63;
    #pragma unroll
    for (int k = 0; k < 16; ++k) {
        int ci = 4 * k + ty;
        float v = tgt[((long)b * Cc + c0 + ci) * Mm + m0 + tx];
        lds[ci][tx] = v;
        tcm[((long)b * VROWS + c0 + ci) * Mm + m0 + tx] = f2bf(v);
    }
    __syncthreads();
    #pragma unroll
    for (int k = 0; k < 16; ++k) {
        int mi = 4 * k + ty;
        tmc[((long)b * Mm + m0 + mi) * Cc + c0 + tx] = f2bf(lds[tx][mi]);
    }
}

// ------- prep 3: src_desc_norm f32 -> snc bf16 [b][n][c] -------
__global__ void k_prep_src(const float* __restrict__ src, unsigned short* __restrict__ snc) {
    __shared__ float lds[64][65];
    int b = blockIdx.z, c0 = blockIdx.y * 64, n0 = blockIdx.x * 64;
    int ty = threadIdx.x >> 6, tx = threadIdx.x & 63;
    #pragma unroll
    for (int k = 0; k < 16; ++k)
        lds[4 * k + ty][tx] = src[((long)b * Cc + c0 + 4 * k + ty) * Nn + n0 + tx];
    __syncthreads();
    #pragma unroll
    for (int k = 0; k < 16; ++k) {
        int ni = 4 * k + ty;
        snc[((long)b * Nn + n0 + ni) * Cc + c0 + tx] = f2bf(lds[tx][ni]);
    }
}

// ------- main fused kernel: LDS-staged, double-buffered flash loop -------
// block = 4 waves, 64 n; wave w owns n-subtile nt*64 + w*16. Block sweeps its
// whole 8192-m chunk in 256 steps of 32 m. K tile (32x256) staged with an XOR
// swizzle (pre-swizzled global source); V tile (272x32) staged linearly.
__global__ __launch_bounds__(256) void k_main(const unsigned short* __restrict__ tmc,
                                              const unsigned short* __restrict__ tcm,
                                              const unsigned short* __restrict__ snc,
                                              const float* __restrict__ scl,
                                              float* __restrict__ part,
                                              float* __restrict__ zp,
                                              float* __restrict__ pp) {
    __shared__ __align__(16) unsigned short kb0[8192], kb1[8192];   // 16 KB each
    __shared__ __align__(16) unsigned short vb0[8704], vb1[8704];   // 17 KB each
    __shared__ __align__(16) unsigned short pbuf[4][16][32];        // 4 KB

    int w = threadIdx.x >> 6, lane = threadIdx.x & 63;
    int l15 = lane & 15, lg = lane >> 4;
    int b = blockIdx.z, nt = blockIdx.y, mc = blockIdx.x;
    int nb = nt * 64 + w * 16;
    long mbase = (long)mc * (Mm / MCn);

    // Q^T B-fragments: lane holds Q[n=l15][c = cc*32 + lg*8 .. +7]
    const unsigned short* qp = snc + ((long)b * Nn + nb + l15) * Cc + lg * 8;
    s16x8 qf[8];
    #pragma unroll
    for (int cc = 0; cc < 8; ++cc) qf[cc] = *(const s16x8*)(qp + cc * 32);

    f32x4 acc[17];
    #pragma unroll
    for (int t = 0; t < 17; ++t) acc[t] = (f32x4){0.f, 0.f, 0.f, 0.f};
    float zacc = 0.f, pmax = 0.f;

    // ---- staging source pointers (per-lane, pre-swizzled for K) ----
    const unsigned short* tmcb = tmc + (long)b * Mm * Cc;
    const unsigned short* tcmb = tcm + (long)b * VROWS * (long)Mm;
    const unsigned short* ksrc[4];
    #pragma unroll
    for (int i = 0; i < 4; ++i) {
        int ins = w * 4 + i;                 // K instr 0..15, covers rows 2*ins, 2*ins+1
        int row = 2 * ins + (lane >> 5);
        int gs  = (lane & 31) ^ (row & 7);   // pre-swizzled 16B slot
        ksrc[i] = tmcb + (mbase + row) * Cc + gs * 8;
    }
    const unsigned short* vsrc[5];
    #pragma unroll
    for (int i = 0; i < 5; ++i) {
        int ins = (i < 4) ? (w * 4 + i) : 16;  // V instr 0..16, covers 16 rows
        int row = ins * 16 + (lane >> 2);
        vsrc[i] = tcmb + (long)row * Mm + mbase + (lane & 3) * 8;
    }

    const float* sclb = scl + (long)b * Mm;

    // stage tile into buffer d
    auto stage = [&](int d) {
        unsigned short* kd = d ? kb1 : kb0;
        unsigned short* vd = d ? vb1 : vb0;
        #pragma unroll
        for (int i = 0; i < 4; ++i) gld_lds16(ksrc[i], kd + (w * 4 + i) * 512);
        #pragma unroll
        for (int i = 0; i < 4; ++i) gld_lds16(vsrc[i], vd + (w * 4 + i) * 512);
        if (w == 3) gld_lds16(vsrc[4], vd + 16 * 512);
    };
    auto advance = [&]() {
        #pragma unroll
        for (int i = 0; i < 4; ++i) ksrc[i] += MSTEP * Cc;
        #pragma unroll
        for (int i = 0; i < 5; ++i) vsrc[i] += MSTEP;
    };

    stage(0);
    advance();
    __syncthreads();

    for (int s = 0; s < NIT; ++s) {
        int cur = s & 1;
        if (s + 1 < NIT) { stage(cur ^ 1); advance(); }
        const unsigned short* kbc = cur ? kb1 : kb0;
        const unsigned short* vbc = cur ? vb1 : vb0;
        long m0 = mbase + (long)s * MSTEP;

        // QK^T: two 16-m subtiles
        int sw = (l15 & 7) << 3;   // K read swizzle (elements)
        #pragma unroll
        for (int t = 0; t < 2; ++t) {
            f32x4 d = (f32x4){0.f, 0.f, 0.f, 0.f};
            const unsigned short* kr = kbc + (t * 16 + l15) * Cc;
            #pragma unroll
            for (int cc = 0; cc < 8; ++cc) {
                s16x8 kf = *(const s16x8*)(kr + ((cc * 32 + lg * 8) ^ sw));
                d = __builtin_amdgcn_mfma_f32_16x16x32_bf16(kf, qf[cc], d, 0, 0, 0);
            }
            float4 sc = *(const float4*)(sclb + m0 + t * 16 + lg * 4);
            float p0 = exp2f(d.x * sc.x);
            float p1 = exp2f(d.y * sc.y);
            float p2 = exp2f(d.z * sc.z);
            float p3 = exp2f(d.w * sc.w);
            zacc += (p0 + p1) + (p2 + p3);
            pmax = fmaxf(pmax, fmaxf(fmaxf(p0, p1), fmaxf(p2, p3)));
            unsigned int lo = (unsigned)f2bf(p0) | ((unsigned)f2bf(p1) << 16);
            unsigned int hi = (unsigned)f2bf(p2) | ((unsigned)f2bf(p3) << 16);
            unsigned int* dst = (unsigned int*)&pbuf[w][l15][t * 16 + lg * 4];
            dst[0] = lo; dst[1] = hi;
        }
        asm volatile("s_waitcnt lgkmcnt(0)" ::: "memory");
        __builtin_amdgcn_sched_barrier(0);
        // P^T B-fragment: lane holds P[n=l15][m-in-32 = lg*8 .. +7]
        s16x8 pf = *(const s16x8*)&pbuf[w][l15][lg * 8];
        // PV: 17 output c-tiles, A = V rows from LDS (contiguous m)
        #pragma unroll
        for (int t = 0; t < 17; ++t) {
            s16x8 vf = *(const s16x8*)(vbc + (t * 16 + l15) * MSTEP + lg * 8);
            acc[t] = __builtin_amdgcn_mfma_f32_16x16x32_bf16(vf, pf, acc[t], 0, 0, 0);
        }
        __syncthreads();
    }

    // per-wave reduce Z / pmax across the 4 lane-groups
    float zt = zacc + __shfl_xor(zacc, 16); zt = zt + __shfl_xor(zt, 32);
    float pt = fmaxf(pmax, __shfl_xor(pmax, 16)); pt = fmaxf(pt, __shfl_xor(pt, 32));
    if (lane < 16) {
        long zi = ((long)(b * MCn + mc)) * Nn + nb + lane;
        zp[zi] = zt;
        pp[zi] = pt;
    }
    float* po = part + (((long)(b * MCn + mc) * Nn) + nb + l15) * VROWS;
    #pragma unroll
    for (int t = 0; t < 17; ++t)
        *(f32x4*)&po[t * 16 + lg * 4] = acc[t];
}

// ------- epilogue: combine m-chunks, normalize, zn(descs), 2D projection, max_softmax -------
__global__ void k_epi(const float* __restrict__ part,
                      const float* __restrict__ zp,
                      const float* __restrict__ pp,
                      float* __restrict__ out) {
    int w = threadIdx.x >> 6, lane = threadIdx.x & 63;
    int bn = blockIdx.x * 4 + w;
    int b = bn >> 10, n = bn & 1023;

    float Z = 0.f, pm = 0.f;
    #pragma unroll
    for (int mc = 0; mc < MCn; ++mc) {
        long zi = ((long)(b * MCn + mc)) * Nn + n;
        Z += zp[zi];
        pm = fmaxf(pm, pp[zi]);
    }
    float invZ = 1.0f / Z;

    float dv[4], s1 = 0.f, s2 = 0.f;
    #pragma unroll
    for (int k = 0; k < 4; ++k) {
        int c = lane + 64 * k;
        float s = 0.f;
        #pragma unroll
        for (int mc = 0; mc < MCn; ++mc)
            s += part[((long)(b * MCn + mc) * Nn + n) * VROWS + c];
        float d = s * invZ;
        dv[k] = d; s1 += d; s2 += d * d;
    }
    #pragma unroll
    for (int off = 1; off < 64; off <<= 1) { s1 += __shfl_xor(s1, off); s2 += __shfl_xor(s2, off); }
    float mean = s1 * (1.0f / 256.0f);
    float var = fmaxf((s2 - 256.0f * mean * mean) * (1.0f / 255.0f), 1e-20f);
    float istd = 1.0f / sqrtf(var);
    #pragma unroll
    for (int k = 0; k < 4; ++k)
        out[O_DESC + ((long)b * Cc + lane + 64 * k) * Nn + n] = (dv[k] - mean) * istd;

    float ex = 0.f;
    if (lane < 4) {
        int c = 256 + lane;
        #pragma unroll
        for (int mc = 0; mc < MCn; ++mc)
            ex += part[((long)(b * MCn + mc) * Nn + n) * VROWS + c];
        ex *= invZ;
    }
    float pc0 = __shfl(ex, 0), pc1 = __shfl(ex, 1), pc2 = __shfl(ex, 2), wv = __shfl(ex, 3);
    if (lane == 0) {
        out[O_COORD + ((long)b * 3 + 0) * Nn + n] = pc0;
        out[O_COORD + ((long)b * 3 + 1) * Nn + n] = pc1;
        out[O_COORD + ((long)b * 3 + 2) * Nn + n] = pc2;
        out[O_W + (long)b * Nn + n] = wv;
        const float cmin = 33.048f;                 // (256/2 - 0.5) * 0.2592
        out[O_P2D + ((long)b * Nn + n) * 2 + 0] = (cmin + pc1) * (1.0f / 0.2592f);
        out[O_P2D + ((long)b * Nn + n) * 2 + 1] = (cmin - pc0) * (1.0f / 0.2592f);
        out[O_VALID + (long)b * Nn + n] = 1.0f;
        atomicMax((unsigned int*)out + O_MAXSM + b, __float_as_uint(pm * invZ));
    }
}

extern "C" void kernel_launch(void* const* d_in, const int* in_sizes, int n_in,
                              void* d_out, int out_size, void* d_ws, size_t ws_size,
                              hipStream_t stream) {
    const float* tgt_coords  = (const float*)d_in[1];
    const float* tgt_weights = (const float*)d_in[3];
    const float* src_desc    = (const float*)d_in[5];
    const float* tgt_desc    = (const float*)d_in[6];

    char* ws = (char*)d_ws;
    float* scl           = (float*)(ws + SCL_OFF);
    unsigned short* tmc  = (unsigned short*)(ws + TMC_OFF);
    unsigned short* tcm  = (unsigned short*)(ws + TCM_OFF);
    unsigned short* snc  = (unsigned short*)(ws + SNC_OFF);
    float* part          = (float*)(ws + PART_OFF);
    float* zp            = (float*)(ws + ZP_OFF);
    float* pp            = (float*)(ws + PP_OFF);
    float* out           = (float*)d_out;

    k_prep_stats<<<dim3(Mm / 256, Bb), 256, 0, stream>>>(tgt_desc, tgt_coords, tgt_weights, scl, tcm);
    k_prep_tgt<<<dim3(Mm / 64, Cc / 64, Bb), 256, 0, stream>>>(tgt_desc, tmc, tcm);
    k_prep_src<<<dim3(Nn / 64, Cc / 64, Bb), 256, 0, stream>>>(src_desc, snc);
    k_main<<<dim3(MCn, Nn / 64, Bb), 256, 0, stream>>>(tmc, tcm, snc, scl, part, zp, pp);
    hipMemsetAsync((char*)d_out + O_MAXSM * 4, 0, 2 * sizeof(float), stream);
    k_epi<<<dim3((Bb * Nn) / 4), 256, 0, stream>>>(part, zp, pp, out);
}

// Round 4
// 422.912 us; speedup vs baseline: 2.8192x; 1.2814x over previous
//
#include <hip/hip_runtime.h>
#include <hip/hip_bf16.h>

// ---------------- problem constants ----------------
#define Bb   2
#define Cc   256
#define Nn   1024
#define Mm   65536
#define MCn  16           // m-chunks (global partials, bf16)
#define VROWS 272         // 256 desc + 3 coords + 1 weight + 12 pad
#define MSTEP 32
#define MCHUNK (Mm / MCn)           // 4096
#define NIT  (MCHUNK / MSTEP)       // 128 K-steps per block

// workspace byte offsets
#define SCL_OFF  0L                               // B*M f32           (0.5 MB)
#define TMC_OFF  524288L                          // B*M*C bf16        (67 MB)   K: [b][m][c]
#define TCM_OFF  67633152L                        // B*272*M bf16      (71.3 MB) V: [b][row][m]
#define SNC_OFF  138936320L                       // B*N*C bf16        (1 MB)    Q^T: [b][n][c]
#define PART_OFF 139984896L                       // B*16*N*272 bf16   (17.8 MB)
#define ZP_OFF   157810688L                       // B*16*N f32
#define PP_OFF   157941760L                       // B*16*N f32  (end 158072832)

// output float offsets
#define O_COORD 0L
#define O_W     6144L
#define O_DESC  8192L
#define O_P2D   532480L
#define O_VALID 536576L
#define O_MAXSM 538624L

using f32x4 = __attribute__((ext_vector_type(4))) float;
using s16x8 = __attribute__((ext_vector_type(8))) short;

__device__ inline unsigned short f2bf(float x) {
    union { float f; unsigned int u; } v; v.f = x;
    unsigned int r = v.u + 0x7FFFu + ((v.u >> 16) & 1u);   // RNE
    return (unsigned short)(r >> 16);
}
__device__ inline float bf2f(unsigned short u) {
    union { unsigned int u; float f; } v; v.u = ((unsigned int)u) << 16;
    return v.f;
}

__device__ inline void gld_lds16(const unsigned short* g, unsigned short* l) {
    __builtin_amdgcn_global_load_lds(
        (const __attribute__((address_space(1))) unsigned int*)g,
        (__attribute__((address_space(3))) unsigned int*)l, 16, 0, 0);
}

// ------- prep 1: per-column stats -> scl, plus extra rows of V (coords/weights) -------
__global__ void k_prep_stats(const float* __restrict__ tgt_desc,
                             const float* __restrict__ coords,
                             const float* __restrict__ weights,
                             float* __restrict__ scl,
                             unsigned short* __restrict__ tcm) {
    int b = blockIdx.y;
    long m = (long)blockIdx.x * 256 + threadIdx.x;
    const float* col = tgt_desc + (long)b * Cc * Mm + m;
    float s = 0.f, s2 = 0.f;
    for (int c = 0; c < Cc; ++c) { float v = col[(long)c * Mm]; s += v; s2 += v * v; }
    float var = fmaxf((s2 - s * s * (1.0f / Cc)) * (1.0f / (Cc - 1)), 1e-20f);
    scl[(long)b * Mm + m] = 1.4426950408889634f * rsqrtf(var) * (1.0f / (Cc * 0.01f));
    unsigned short* vrow = tcm + ((long)b * VROWS + 256) * Mm + m;
    #pragma unroll
    for (int i = 0; i < 3; ++i) vrow[(long)i * Mm] = f2bf(coords[((long)b * 3 + i) * Mm + m]);
    vrow[3L * Mm] = f2bf(weights[(long)b * Mm + m]);
    #pragma unroll
    for (int i = 4; i < 16; ++i) vrow[(long)i * Mm] = 0;
}

// ------- prep 2: tgt_desc f32 -> tmc bf16 [b][m][c] + tcm bf16 [b][c][m] -------
__global__ void k_prep_tgt(const float* __restrict__ tgt,
                           unsigned short* __restrict__ tmc,
                           unsigned short* __restrict__ tcm) {
    __shared__ float lds[64][65];
    int b = blockIdx.z, c0 = blockIdx.y * 64;
    long m0 = (long)blockIdx.x * 64;
    int ty = threadIdx.x >> 6, tx = threadIdx.x & 63;
    #pragma unroll
    for (int k = 0; k < 16; ++k) {
        int ci = 4 * k + ty;
        float v = tgt[((long)b * Cc + c0 + ci) * Mm + m0 + tx];
        lds[ci][tx] = v;
        tcm[((long)b * VROWS + c0 + ci) * Mm + m0 + tx] = f2bf(v);
    }
    __syncthreads();
    #pragma unroll
    for (int k = 0; k < 16; ++k) {
        int mi = 4 * k + ty;
        tmc[((long)b * Mm + m0 + mi) * Cc + c0 + tx] = f2bf(lds[tx][mi]);
    }
}

// ------- prep 3: src_desc_norm f32 -> snc bf16 [b][n][c] -------
__global__ void k_prep_src(const float* __restrict__ src, unsigned short* __restrict__ snc) {
    __shared__ float lds[64][65];
    int b = blockIdx.z, c0 = blockIdx.y * 64, n0 = blockIdx.x * 64;
    int ty = threadIdx.x >> 6, tx = threadIdx.x & 63;
    #pragma unroll
    for (int k = 0; k < 16; ++k)
        lds[4 * k + ty][tx] = src[((long)b * Cc + c0 + 4 * k + ty) * Nn + n0 + tx];
    __syncthreads();
    #pragma unroll
    for (int k = 0; k < 16; ++k) {
        int ni = 4 * k + ty;
        snc[((long)b * Nn + n0 + ni) * Cc + c0 + tx] = f2bf(lds[tx][ni]);
    }
}

// ------- main fused kernel: LDS-staged, double-buffered, 32 n per wave -------
// block = 4 waves * 32 n = 128 n; block sweeps a 4096-m chunk in 128 steps of 32 m.
// K tile (32x256) XOR-swizzled; V tile (272x32) chunk-XOR-swizzled; both staged
// via pre-swizzled global_load_lds sources. Each K/V fragment feeds 2 MFMAs.
__global__ __launch_bounds__(256, 1) void k_main(const unsigned short* __restrict__ tmc,
                                                 const unsigned short* __restrict__ tcm,
                                                 const unsigned short* __restrict__ snc,
                                                 const float* __restrict__ scl,
                                                 unsigned short* __restrict__ part,
                                                 float* __restrict__ zp,
                                                 float* __restrict__ pp) {
    __shared__ __align__(16) unsigned short kb0[8192], kb1[8192];   // 16 KB each
    __shared__ __align__(16) unsigned short vb0[8704], vb1[8704];   // 17 KB each
    __shared__ __align__(16) unsigned short pbuf[4][2][16][56];     // 14 KB, padded rows (112B = 7*16B)

    int w = threadIdx.x >> 6, lane = threadIdx.x & 63;
    int l15 = lane & 15, lg = lane >> 4;
    int b = blockIdx.z, nt = blockIdx.y, mc = blockIdx.x;
    int nb = nt * 128 + w * 32;
    long mbase = (long)mc * MCHUNK;

    // Q^T B-fragments for 2 n-subtiles: lane holds Q[n][c = cc*32 + lg*8 .. +7]
    s16x8 qf[2][8];
    #pragma unroll
    for (int st = 0; st < 2; ++st) {
        const unsigned short* qp = snc + ((long)b * Nn + nb + st * 16 + l15) * Cc + lg * 8;
        #pragma unroll
        for (int cc = 0; cc < 8; ++cc) qf[st][cc] = *(const s16x8*)(qp + cc * 32);
    }

    f32x4 acc[2][17];
    #pragma unroll
    for (int st = 0; st < 2; ++st)
        #pragma unroll
        for (int t = 0; t < 17; ++t) acc[st][t] = (f32x4){0.f, 0.f, 0.f, 0.f};
    float zacc[2] = {0.f, 0.f}, pmax[2] = {0.f, 0.f};

    // ---- staging source pointers (per-lane, pre-swizzled) ----
    const unsigned short* tmcb = tmc + (long)b * Mm * Cc;
    const unsigned short* tcmb = tcm + (long)b * VROWS * (long)Mm;
    const unsigned short* ksrc[4];
    #pragma unroll
    for (int i = 0; i < 4; ++i) {
        int ins = w * 4 + i;                 // K instr 0..15, covers rows 2*ins, 2*ins+1
        int row = 2 * ins + (lane >> 5);
        int gs  = (lane & 31) ^ (row & 7);   // pre-swizzled 16B slot
        ksrc[i] = tmcb + (mbase + row) * Cc + gs * 8;
    }
    const unsigned short* vsrc[5];
    int vj = ((lane & 3) ^ ((lane >> 3) & 3)) * 8;   // chunk-XOR pre-swizzle (m offset)
    #pragma unroll
    for (int i = 0; i < 5; ++i) {
        int ins = (i < 4) ? (w * 4 + i) : 16;  // V instr 0..16, covers 16 rows
        int row = ins * 16 + (lane >> 2);
        vsrc[i] = tcmb + (long)row * Mm + mbase + vj;
    }

    const float* sclb = scl + (long)b * Mm;

    auto stage = [&](int d) {
        unsigned short* kd = d ? kb1 : kb0;
        unsigned short* vd = d ? vb1 : vb0;
        #pragma unroll
        for (int i = 0; i < 4; ++i) gld_lds16(ksrc[i], kd + (w * 4 + i) * 512);
        #pragma unroll
        for (int i = 0; i < 4; ++i) gld_lds16(vsrc[i], vd + (w * 4 + i) * 512);
        if (w == 3) gld_lds16(vsrc[4], vd + 16 * 512);
    };
    auto advance = [&]() {
        #pragma unroll
        for (int i = 0; i < 4; ++i) ksrc[i] += MSTEP * Cc;
        #pragma unroll
        for (int i = 0; i < 5; ++i) vsrc[i] += MSTEP;
    };

    stage(0);
    advance();
    __syncthreads();

    int ksw = (l15 & 7) << 3;              // K read swizzle (elements)
    int vsw = (lg ^ ((l15 >> 1) & 3)) * 8; // V read chunk swizzle (elements)

    for (int s = 0; s < NIT; ++s) {
        int cur = s & 1;
        if (s + 1 < NIT) { stage(cur ^ 1); advance(); }
        const unsigned short* kbc = cur ? kb1 : kb0;
        const unsigned short* vbc = cur ? vb1 : vb0;
        long m0 = mbase + (long)s * MSTEP;

        // QK^T: two 16-m subtiles x two 16-n subtiles; K-frag shared across n
        #pragma unroll
        for (int t = 0; t < 2; ++t) {
            f32x4 dA = (f32x4){0.f, 0.f, 0.f, 0.f};
            f32x4 dB = (f32x4){0.f, 0.f, 0.f, 0.f};
            const unsigned short* kr = kbc + (t * 16 + l15) * Cc;
            #pragma unroll
            for (int cc = 0; cc < 8; ++cc) {
                s16x8 kf = *(const s16x8*)(kr + ((cc * 32 + lg * 8) ^ ksw));
                dA = __builtin_amdgcn_mfma_f32_16x16x32_bf16(kf, qf[0][cc], dA, 0, 0, 0);
                dB = __builtin_amdgcn_mfma_f32_16x16x32_bf16(kf, qf[1][cc], dB, 0, 0, 0);
            }
            float4 sc = *(const float4*)(sclb + m0 + t * 16 + lg * 4);
            #pragma unroll
            for (int st = 0; st < 2; ++st) {
                f32x4 d = st ? dB : dA;
                float p0 = exp2f(d.x * sc.x);
                float p1 = exp2f(d.y * sc.y);
                float p2 = exp2f(d.z * sc.z);
                float p3 = exp2f(d.w * sc.w);
                zacc[st] += (p0 + p1) + (p2 + p3);
                pmax[st] = fmaxf(pmax[st], fmaxf(fmaxf(p0, p1), fmaxf(p2, p3)));
                unsigned long long pk =
                    (unsigned long long)((unsigned)f2bf(p0) | ((unsigned)f2bf(p1) << 16)) |
                    ((unsigned long long)((unsigned)f2bf(p2) | ((unsigned)f2bf(p3) << 16)) << 32);
                *(unsigned long long*)&pbuf[w][st][l15][t * 16 + lg * 4] = pk;
            }
        }
        asm volatile("s_waitcnt lgkmcnt(0)" ::: "memory");
        __builtin_amdgcn_sched_barrier(0);
        // P^T B-fragments: lane holds P[n=l15][m-in-32 = lg*8 .. +7]
        s16x8 pfA = *(const s16x8*)&pbuf[w][0][l15][lg * 8];
        s16x8 pfB = *(const s16x8*)&pbuf[w][1][l15][lg * 8];
        // PV: 17 output c-tiles; V-frag shared across both n-subtiles
        #pragma unroll
        for (int t = 0; t < 17; ++t) {
            s16x8 vf = *(const s16x8*)(vbc + (t * 16 + l15) * MSTEP + vsw);
            acc[0][t] = __builtin_amdgcn_mfma_f32_16x16x32_bf16(vf, pfA, acc[0][t], 0, 0, 0);
            acc[1][t] = __builtin_amdgcn_mfma_f32_16x16x32_bf16(vf, pfB, acc[1][t], 0, 0, 0);
        }
        __syncthreads();
    }

    // reduce Z / pmax across the 4 lane-groups; write partials (bf16)
    #pragma unroll
    for (int st = 0; st < 2; ++st) {
        float zt = zacc[st] + __shfl_xor(zacc[st], 16); zt = zt + __shfl_xor(zt, 32);
        float pt = fmaxf(pmax[st], __shfl_xor(pmax[st], 16)); pt = fmaxf(pt, __shfl_xor(pt, 32));
        if (lane < 16) {
            long zi = ((long)(b * MCn + mc)) * Nn + nb + st * 16 + lane;
            zp[zi] = zt;
            pp[zi] = pt;
        }
        unsigned short* po = part + (((long)(b * MCn + mc) * Nn) + nb + st * 16 + l15) * VROWS;
        #pragma unroll
        for (int t = 0; t < 17; ++t) {
            f32x4 a = acc[st][t];
            unsigned long long pk =
                (unsigned long long)((unsigned)f2bf(a.x) | ((unsigned)f2bf(a.y) << 16)) |
                ((unsigned long long)((unsigned)f2bf(a.z) | ((unsigned)f2bf(a.w) << 16)) << 32);
            *(unsigned long long*)&po[t * 16 + lg * 4] = pk;
        }
    }
}

// ------- epilogue: combine m-chunks, normalize, zn(descs), 2D projection, max_softmax -------
__global__ void k_epi(const unsigned short* __restrict__ part,
                      const float* __restrict__ zp,
                      const float* __restrict__ pp,
                      float* __restrict__ out) {
    int w = threadIdx.x >> 6, lane = threadIdx.x & 63;
    int bn = blockIdx.x * 4 + w;
    int b = bn >> 10, n = bn & 1023;

    float Z = 0.f, pm = 0.f;
    #pragma unroll
    for (int mc = 0; mc < MCn; ++mc) {
        long zi = ((long)(b * MCn + mc)) * Nn + n;
        Z += zp[zi];
        pm = fmaxf(pm, pp[zi]);
    }
    float invZ = 1.0f / Z;

    float dv[4], s1 = 0.f, s2 = 0.f;
    #pragma unroll
    for (int k = 0; k < 4; ++k) {
        int c = lane + 64 * k;
        float s = 0.f;
        #pragma unroll
        for (int mc = 0; mc < MCn; ++mc)
            s += bf2f(part[((long)(b * MCn + mc) * Nn + n) * VROWS + c]);
        float d = s * invZ;
        dv[k] = d; s1 += d; s2 += d * d;
    }
    #pragma unroll
    for (int off = 1; off < 64; off <<= 1) { s1 += __shfl_xor(s1, off); s2 += __shfl_xor(s2, off); }
    float mean = s1 * (1.0f / 256.0f);
    float var = fmaxf((s2 - 256.0f * mean * mean) * (1.0f / 255.0f), 1e-20f);
    float istd = 1.0f / sqrtf(var);
    #pragma unroll
    for (int k = 0; k < 4; ++k)
        out[O_DESC + ((long)b * Cc + lane + 64 * k) * Nn + n] = (dv[k] - mean) * istd;

    float ex = 0.f;
    if (lane < 4) {
        int c = 256 + lane;
        #pragma unroll
        for (int mc = 0; mc < MCn; ++mc)
            ex += bf2f(part[((long)(b * MCn + mc) * Nn + n) * VROWS + c]);
        ex *= invZ;
    }
    float pc0 = __shfl(ex, 0), pc1 = __shfl(ex, 1), pc2 = __shfl(ex, 2), wv = __shfl(ex, 3);
    if (lane == 0) {
        out[O_COORD + ((long)b * 3 + 0) * Nn + n] = pc0;
        out[O_COORD + ((long)b * 3 + 1) * Nn + n] = pc1;
        out[O_COORD + ((long)b * 3 + 2) * Nn + n] = pc2;
        out[O_W + (long)b * Nn + n] = wv;
        const float cmin = 33.048f;                 // (256/2 - 0.5) * 0.2592
        out[O_P2D + ((long)b * Nn + n) * 2 + 0] = (cmin + pc1) * (1.0f / 0.2592f);
        out[O_P2D + ((long)b * Nn + n) * 2 + 1] = (cmin - pc0) * (1.0f / 0.2592f);
        out[O_VALID + (long)b * Nn + n] = 1.0f;
        atomicMax((unsigned int*)out + O_MAXSM + b, __float_as_uint(pm * invZ));
    }
}

extern "C" void kernel_launch(void* const* d_in, const int* in_sizes, int n_in,
                              void* d_out, int out_size, void* d_ws, size_t ws_size,
                              hipStream_t stream) {
    const float* tgt_coords  = (const float*)d_in[1];
    const float* tgt_weights = (const float*)d_in[3];
    const float* src_desc    = (const float*)d_in[5];
    const float* tgt_desc    = (const float*)d_in[6];

    char* ws = (char*)d_ws;
    float* scl           = (float*)(ws + SCL_OFF);
    unsigned short* tmc  = (unsigned short*)(ws + TMC_OFF);
    unsigned short* tcm  = (unsigned short*)(ws + TCM_OFF);
    unsigned short* snc  = (unsigned short*)(ws + SNC_OFF);
    unsigned short* part = (unsigned short*)(ws + PART_OFF);
    float* zp            = (float*)(ws + ZP_OFF);
    float* pp            = (float*)(ws + PP_OFF);
    float* out           = (float*)d_out;

    k_prep_stats<<<dim3(Mm / 256, Bb), 256, 0, stream>>>(tgt_desc, tgt_coords, tgt_weights, scl, tcm);
    k_prep_tgt<<<dim3(Mm / 64, Cc / 64, Bb), 256, 0, stream>>>(tgt_desc, tmc, tcm);
    k_prep_src<<<dim3(Nn / 64, Cc / 64, Bb), 256, 0, stream>>>(src_desc, snc);
    k_main<<<dim3(MCn, Nn / 128, Bb), 256, 0, stream>>>(tmc, tcm, snc, scl, part, zp, pp);
    hipMemsetAsync((char*)d_out + O_MAXSM * 4, 0, 2 * sizeof(float), stream);
    k_epi<<<dim3((Bb * Nn) / 4), 256, 0, stream>>>(part, zp, pp, out);
}

// Round 5
// 336.638 us; speedup vs baseline: 3.5417x; 1.2563x over previous
//
#include <hip/hip_runtime.h>
#include <hip/hip_bf16.h>

// ---------------- problem constants ----------------
#define Bb   2
#define Cc   256
#define Nn   1024
#define Mm   65536
#define MCn  16           // m-chunks (global partials, bf16)
#define VROWS 272         // 256 desc + 3 coords + 1 weight + ones + 11 pad
#define MSTEP 32
#define MCHUNK (Mm / MCn)           // 4096
#define NIT  (MCHUNK / MSTEP)       // 128 K-steps per block

// workspace byte offsets
#define SCL_OFF  0L                               // B*M f32           (0.5 MB)
#define TMC_OFF  524288L                          // B*M*C bf16        (67 MB)   K: [b][m][c]
#define TCM_OFF  67633152L                        // B*272*M bf16      (71.3 MB) V: [b][row][m]
#define SNC_OFF  138936320L                       // B*N*C bf16        (1 MB)    Q^T: [b][n][c]
#define PART_OFF 139984896L                       // B*16*N*272 bf16   (17.8 MB)
#define ZP_OFF   157810688L                       // B*16*N f32
#define PP_OFF   157941760L                       // B*16*N f32  (end 158072832)
// stats partials live in the part region (used before k_main writes part)
#define PS_OFF   PART_OFF                         // [B][4][M] f32 sums   (2 MB)
#define PS2_OFF  (PART_OFF + 2097152L)            // [B][4][M] f32 sumsq  (2 MB)

// output float offsets
#define O_COORD 0L
#define O_W     6144L
#define O_DESC  8192L
#define O_P2D   532480L
#define O_VALID 536576L
#define O_MAXSM 538624L

using f32x4 = __attribute__((ext_vector_type(4))) float;
using s16x8 = __attribute__((ext_vector_type(8))) short;

__device__ inline unsigned short f2bf(float x) {
    union { float f; unsigned int u; } v; v.f = x;
    unsigned int r = v.u + 0x7FFFu + ((v.u >> 16) & 1u);   // RNE
    return (unsigned short)(r >> 16);
}
__device__ inline float bf2f(unsigned short u) {
    union { unsigned int u; float f; } v; v.u = ((unsigned int)u) << 16;
    return v.f;
}
__device__ inline float exp2v(float x) {
    float r; asm("v_exp_f32 %0, %1" : "=v"(r) : "v"(x)); return r;
}
__device__ inline unsigned int cvtpk(float lo, float hi) {
    unsigned int r;
    asm("v_cvt_pk_bf16_f32 %0, %1, %2" : "=v"(r) : "v"(lo), "v"(hi));
    return r;
}

__device__ inline void gld_lds16(const unsigned short* g, unsigned short* l) {
    __builtin_amdgcn_global_load_lds(
        (const __attribute__((address_space(1))) unsigned int*)g,
        (__attribute__((address_space(3))) unsigned int*)l, 16, 0, 0);
}

// ------- prep A: tgt_desc f32 -> tmc bf16 [b][m][c] + tcm bf16 [b][c][m],
//                 plus per-(c-block, m) partial sums for the column stats -------
__global__ void k_prep_tgt(const float* __restrict__ tgt,
                           unsigned short* __restrict__ tmc,
                           unsigned short* __restrict__ tcm,
                           float* __restrict__ ps,
                           float* __restrict__ ps2) {
    __shared__ float lds[64][65];
    __shared__ float sm[4][64], sm2[4][64];
    int b = blockIdx.z, cy = blockIdx.y, c0 = cy * 64;
    long m0 = (long)blockIdx.x * 64;
    int ty = threadIdx.x >> 6, tx = threadIdx.x & 63;
    float s = 0.f, s2 = 0.f;
    #pragma unroll
    for (int k = 0; k < 16; ++k) {
        int ci = 4 * k + ty;
        float v = tgt[((long)b * Cc + c0 + ci) * Mm + m0 + tx];
        lds[ci][tx] = v;
        s += v; s2 += v * v;
        tcm[((long)b * VROWS + c0 + ci) * Mm + m0 + tx] = f2bf(v);
    }
    sm[ty][tx] = s; sm2[ty][tx] = s2;
    __syncthreads();
    #pragma unroll
    for (int k = 0; k < 16; ++k) {
        int mi = 4 * k + ty;
        tmc[((long)b * Mm + m0 + mi) * Cc + c0 + tx] = f2bf(lds[tx][mi]);
    }
    if (ty == 0) {
        long o = ((long)b * 4 + cy) * Mm + m0 + tx;
        ps[o]  = (sm[0][tx] + sm[1][tx]) + (sm[2][tx] + sm[3][tx]);
        ps2[o] = (sm2[0][tx] + sm2[1][tx]) + (sm2[2][tx] + sm2[3][tx]);
    }
}

// ------- prep B: finish stats -> scl; write coords/weights/ones rows of V -------
__global__ void k_stats(const float* __restrict__ ps,
                        const float* __restrict__ ps2,
                        const float* __restrict__ coords,
                        const float* __restrict__ weights,
                        float* __restrict__ scl,
                        unsigned short* __restrict__ tcm) {
    int b = blockIdx.y;
    long m = (long)blockIdx.x * 256 + threadIdx.x;
    float s = 0.f, s2 = 0.f;
    #pragma unroll
    for (int k = 0; k < 4; ++k) {
        long o = ((long)b * 4 + k) * Mm + m;
        s += ps[o]; s2 += ps2[o];
    }
    float var = fmaxf((s2 - s * s * (1.0f / Cc)) * (1.0f / (Cc - 1)), 1e-20f);
    scl[(long)b * Mm + m] = 1.4426950408889634f * rsqrtf(var) * (1.0f / (Cc * 0.01f));
    unsigned short* vrow = tcm + ((long)b * VROWS + 256) * Mm + m;
    #pragma unroll
    for (int i = 0; i < 3; ++i) vrow[(long)i * Mm] = f2bf(coords[((long)b * 3 + i) * Mm + m]);
    vrow[3L * Mm] = f2bf(weights[(long)b * Mm + m]);
    vrow[4L * Mm] = 0x3F80;   // ones row (channel 260): Z comes out of the PV MFMA
    #pragma unroll
    for (int i = 5; i < 16; ++i) vrow[(long)i * Mm] = 0;
}

// ------- prep C: src_desc_norm f32 -> snc bf16 [b][n][c] -------
__global__ void k_prep_src(const float* __restrict__ src, unsigned short* __restrict__ snc) {
    __shared__ float lds[64][65];
    int b = blockIdx.z, c0 = blockIdx.y * 64, n0 = blockIdx.x * 64;
    int ty = threadIdx.x >> 6, tx = threadIdx.x & 63;
    #pragma unroll
    for (int k = 0; k < 16; ++k)
        lds[4 * k + ty][tx] = src[((long)b * Cc + c0 + 4 * k + ty) * Nn + n0 + tx];
    __syncthreads();
    #pragma unroll
    for (int k = 0; k < 16; ++k) {
        int ni = 4 * k + ty;
        snc[((long)b * Nn + n0 + ni) * Cc + c0 + tx] = f2bf(lds[tx][ni]);
    }
}

// ------- main fused kernel: LDS-staged, double-buffered, 32 n per wave -------
__global__ __launch_bounds__(256, 1) void k_main(const unsigned short* __restrict__ tmc,
                                                 const unsigned short* __restrict__ tcm,
                                                 const unsigned short* __restrict__ snc,
                                                 const float* __restrict__ scl,
                                                 unsigned short* __restrict__ part,
                                                 float* __restrict__ zp,
                                                 float* __restrict__ pp) {
    __shared__ __align__(16) unsigned short kb0[8192], kb1[8192];   // 16 KB each
    __shared__ __align__(16) unsigned short vb0[8704], vb1[8704];   // 17 KB each
    __shared__ __align__(16) unsigned short pbuf[4][2][16][56];     // 14 KB, 112B row stride

    int w = threadIdx.x >> 6, lane = threadIdx.x & 63;
    int l15 = lane & 15, lg = lane >> 4;
    int b = blockIdx.z, nt = blockIdx.y, mc = blockIdx.x;
    int nb = nt * 128 + w * 32;
    long mbase = (long)mc * MCHUNK;

    // Q^T B-fragments for 2 n-subtiles
    s16x8 qf[2][8];
    #pragma unroll
    for (int st = 0; st < 2; ++st) {
        const unsigned short* qp = snc + ((long)b * Nn + nb + st * 16 + l15) * Cc + lg * 8;
        #pragma unroll
        for (int cc = 0; cc < 8; ++cc) qf[st][cc] = *(const s16x8*)(qp + cc * 32);
    }

    f32x4 acc[2][17];
    #pragma unroll
    for (int st = 0; st < 2; ++st)
        #pragma unroll
        for (int t = 0; t < 17; ++t) acc[st][t] = (f32x4){0.f, 0.f, 0.f, 0.f};
    float pmax[2] = {0.f, 0.f};

    // ---- staging source pointers (per-lane, pre-swizzled) ----
    const unsigned short* tmcb = tmc + (long)b * Mm * Cc;
    const unsigned short* tcmb = tcm + (long)b * VROWS * (long)Mm;
    const unsigned short* ksrc[4];
    #pragma unroll
    for (int i = 0; i < 4; ++i) {
        int ins = w * 4 + i;
        int row = 2 * ins + (lane >> 5);
        int gs  = (lane & 31) ^ (row & 7);
        ksrc[i] = tmcb + (mbase + row) * Cc + gs * 8;
    }
    const unsigned short* vsrc[5];
    int vj = ((lane & 3) ^ ((lane >> 3) & 3)) * 8;
    #pragma unroll
    for (int i = 0; i < 5; ++i) {
        int ins = (i < 4) ? (w * 4 + i) : 16;
        int row = ins * 16 + (lane >> 2);
        vsrc[i] = tcmb + (long)row * Mm + mbase + vj;
    }

    const float* sclb = scl + (long)b * Mm;

    auto stage = [&](int d) {
        unsigned short* kd = d ? kb1 : kb0;
        unsigned short* vd = d ? vb1 : vb0;
        #pragma unroll
        for (int i = 0; i < 4; ++i) gld_lds16(ksrc[i], kd + (w * 4 + i) * 512);
        #pragma unroll
        for (int i = 0; i < 4; ++i) gld_lds16(vsrc[i], vd + (w * 4 + i) * 512);
        if (w == 3) gld_lds16(vsrc[4], vd + 16 * 512);
    };
    auto advance = [&]() {
        #pragma unroll
        for (int i = 0; i < 4; ++i) ksrc[i] += MSTEP * Cc;
        #pragma unroll
        for (int i = 0; i < 5; ++i) vsrc[i] += MSTEP;
    };

    stage(0);
    advance();
    __syncthreads();

    int ksw = (l15 & 7) << 3;              // K read swizzle (elements)
    int vsw = (lg ^ ((l15 >> 1) & 3)) * 8; // V read chunk swizzle (elements)

    // software-pipelined scl (registers one iteration ahead)
    float4 scA = *(const float4*)(sclb + mbase + lg * 4);
    float4 scB = *(const float4*)(sclb + mbase + 16 + lg * 4);

    for (int s = 0; s < NIT; ++s) {
        int cur = s & 1;
        if (s + 1 < NIT) { stage(cur ^ 1); advance(); }
        const unsigned short* kbc = cur ? kb1 : kb0;
        const unsigned short* vbc = cur ? vb1 : vb0;
        int sn = (s + 1 < NIT) ? s + 1 : s;
        float4 nA = *(const float4*)(sclb + mbase + (long)sn * MSTEP + lg * 4);
        float4 nB = *(const float4*)(sclb + mbase + (long)sn * MSTEP + 16 + lg * 4);

        // QK^T: two 16-m subtiles x two 16-n subtiles; K-frag shared across n
        #pragma unroll
        for (int t = 0; t < 2; ++t) {
            f32x4 dA = (f32x4){0.f, 0.f, 0.f, 0.f};
            f32x4 dB = (f32x4){0.f, 0.f, 0.f, 0.f};
            const unsigned short* kr = kbc + (t * 16 + l15) * Cc;
            #pragma unroll
            for (int cc = 0; cc < 8; ++cc) {
                s16x8 kf = *(const s16x8*)(kr + ((cc * 32 + lg * 8) ^ ksw));
                dA = __builtin_amdgcn_mfma_f32_16x16x32_bf16(kf, qf[0][cc], dA, 0, 0, 0);
                dB = __builtin_amdgcn_mfma_f32_16x16x32_bf16(kf, qf[1][cc], dB, 0, 0, 0);
            }
            float4 sc = t ? scB : scA;
            #pragma unroll
            for (int st = 0; st < 2; ++st) {
                f32x4 d = st ? dB : dA;
                float p0 = exp2v(d.x * sc.x);
                float p1 = exp2v(d.y * sc.y);
                float p2 = exp2v(d.z * sc.z);
                float p3 = exp2v(d.w * sc.w);
                pmax[st] = fmaxf(pmax[st], fmaxf(fmaxf(p0, p1), fmaxf(p2, p3)));
                unsigned long long pk =
                    (unsigned long long)cvtpk(p0, p1) | ((unsigned long long)cvtpk(p2, p3) << 32);
                *(unsigned long long*)&pbuf[w][st][l15][t * 16 + lg * 4] = pk;
            }
        }
        // P^T B-fragments (compiler inserts the precise lgkmcnt for the RAW dep)
        s16x8 pfA = *(const s16x8*)&pbuf[w][0][l15][lg * 8];
        s16x8 pfB = *(const s16x8*)&pbuf[w][1][l15][lg * 8];
        // PV: 17 output c-tiles; V-frag shared across both n-subtiles
        #pragma unroll
        for (int t = 0; t < 17; ++t) {
            s16x8 vf = *(const s16x8*)(vbc + (t * 16 + l15) * MSTEP + vsw);
            acc[0][t] = __builtin_amdgcn_mfma_f32_16x16x32_bf16(vf, pfA, acc[0][t], 0, 0, 0);
            acc[1][t] = __builtin_amdgcn_mfma_f32_16x16x32_bf16(vf, pfB, acc[1][t], 0, 0, 0);
        }
        scA = nA; scB = nB;
        __syncthreads();
    }

    // Z sits in acc[st][16].x on lanes lg==1 (channel 260 = ones row)
    #pragma unroll
    for (int st = 0; st < 2; ++st) {
        float pt = fmaxf(pmax[st], __shfl_xor(pmax[st], 16));
        pt = fmaxf(pt, __shfl_xor(pt, 32));
        long zi = ((long)(b * MCn + mc)) * Nn + nb + st * 16;
        if (lg == 1) zp[zi + l15] = acc[st][16].x;
        if (lane < 16) pp[zi + lane] = pt;
        unsigned short* po = part + (((long)(b * MCn + mc) * Nn) + nb + st * 16 + l15) * VROWS;
        #pragma unroll
        for (int t = 0; t < 17; ++t) {
            f32x4 a = acc[st][t];
            unsigned long long pk =
                (unsigned long long)cvtpk(a.x, a.y) | ((unsigned long long)cvtpk(a.z, a.w) << 32);
            *(unsigned long long*)&po[t * 16 + lg * 4] = pk;
        }
    }
}

// ------- epilogue: combine m-chunks, normalize, zn(descs), 2D projection, max_softmax -------
__global__ void k_epi(const unsigned short* __restrict__ part,
                      const float* __restrict__ zp,
                      const float* __restrict__ pp,
                      float* __restrict__ out) {
    int w = threadIdx.x >> 6, lane = threadIdx.x & 63;
    int bn = blockIdx.x * 4 + w;
    int b = bn >> 10, n = bn & 1023;

    float Z = 0.f, pm = 0.f;
    #pragma unroll
    for (int mc = 0; mc < MCn; ++mc) {
        long zi = ((long)(b * MCn + mc)) * Nn + n;
        Z += zp[zi];
        pm = fmaxf(pm, pp[zi]);
    }
    float invZ = 1.0f / Z;

    float dv[4], s1 = 0.f, s2 = 0.f;
    #pragma unroll
    for (int k = 0; k < 4; ++k) {
        int c = lane + 64 * k;
        float s = 0.f;
        #pragma unroll
        for (int mc = 0; mc < MCn; ++mc)
            s += bf2f(part[((long)(b * MCn + mc) * Nn + n) * VROWS + c]);
        float d = s * invZ;
        dv[k] = d; s1 += d; s2 += d * d;
    }
    #pragma unroll
    for (int off = 1; off < 64; off <<= 1) { s1 += __shfl_xor(s1, off); s2 += __shfl_xor(s2, off); }
    float mean = s1 * (1.0f / 256.0f);
    float var = fmaxf((s2 - 256.0f * mean * mean) * (1.0f / 255.0f), 1e-20f);
    float istd = 1.0f / sqrtf(var);
    #pragma unroll
    for (int k = 0; k < 4; ++k)
        out[O_DESC + ((long)b * Cc + lane + 64 * k) * Nn + n] = (dv[k] - mean) * istd;

    float ex = 0.f;
    if (lane < 4) {
        int c = 256 + lane;
        #pragma unroll
        for (int mc = 0; mc < MCn; ++mc)
            ex += bf2f(part[((long)(b * MCn + mc) * Nn + n) * VROWS + c]);
        ex *= invZ;
    }
    float pc0 = __shfl(ex, 0), pc1 = __shfl(ex, 1), pc2 = __shfl(ex, 2), wv = __shfl(ex, 3);
    if (lane == 0) {
        out[O_COORD + ((long)b * 3 + 0) * Nn + n] = pc0;
        out[O_COORD + ((long)b * 3 + 1) * Nn + n] = pc1;
        out[O_COORD + ((long)b * 3 + 2) * Nn + n] = pc2;
        out[O_W + (long)b * Nn + n] = wv;
        const float cmin = 33.048f;                 // (256/2 - 0.5) * 0.2592
        out[O_P2D + ((long)b * Nn + n) * 2 + 0] = (cmin + pc1) * (1.0f / 0.2592f);
        out[O_P2D + ((long)b * Nn + n) * 2 + 1] = (cmin - pc0) * (1.0f / 0.2592f);
        out[O_VALID + (long)b * Nn + n] = 1.0f;
        atomicMax((unsigned int*)out + O_MAXSM + b, __float_as_uint(pm * invZ));
    }
}

extern "C" void kernel_launch(void* const* d_in, const int* in_sizes, int n_in,
                              void* d_out, int out_size, void* d_ws, size_t ws_size,
                              hipStream_t stream) {
    const float* tgt_coords  = (const float*)d_in[1];
    const float* tgt_weights = (const float*)d_in[3];
    const float* src_desc    = (const float*)d_in[5];
    const float* tgt_desc    = (const float*)d_in[6];

    char* ws = (char*)d_ws;
    float* scl           = (float*)(ws + SCL_OFF);
    unsigned short* tmc  = (unsigned short*)(ws + TMC_OFF);
    unsigned short* tcm  = (unsigned short*)(ws + TCM_OFF);
    unsigned short* snc  = (unsigned short*)(ws + SNC_OFF);
    unsigned short* part = (unsigned short*)(ws + PART_OFF);
    float* ps            = (float*)(ws + PS_OFF);
    float* ps2           = (float*)(ws + PS2_OFF);
    float* zp            = (float*)(ws + ZP_OFF);
    float* pp            = (float*)(ws + PP_OFF);
    float* out           = (float*)d_out;

    k_prep_tgt<<<dim3(Mm / 64, Cc / 64, Bb), 256, 0, stream>>>(tgt_desc, tmc, tcm, ps, ps2);
    k_stats<<<dim3(Mm / 256, Bb), 256, 0, stream>>>(ps, ps2, tgt_coords, tgt_weights, scl, tcm);
    k_prep_src<<<dim3(Nn / 64, Cc / 64, Bb), 256, 0, stream>>>(src_desc, snc);
    k_main<<<dim3(MCn, Nn / 128, Bb), 256, 0, stream>>>(tmc, tcm, snc, scl, part, zp, pp);
    hipMemsetAsync((char*)d_out + O_MAXSM * 4, 0, 2 * sizeof(float), stream);
    k_epi<<<dim3((Bb * Nn) / 4), 256, 0, stream>>>(part, zp, pp, out);
}

// Round 6
// 324.926 us; speedup vs baseline: 3.6694x; 1.0360x over previous
//
#include <hip/hip_runtime.h>
#include <hip/hip_bf16.h>

// ---------------- problem constants ----------------
#define Bb   2
#define Cc   256
#define Nn   1024
#define Mm   65536
#define MCn  16           // m-chunks (global partials, bf16)
#define VROWS 272         // 256 desc + 3 coords + 1 weight + ones + 11 pad
#define MSTEP 32
#define MCHUNK (Mm / MCn)           // 4096
#define NIT  (MCHUNK / MSTEP)       // 128 K-steps per block

// workspace byte offsets
#define SCL_OFF  0L                               // B*M f32           (0.5 MB)
#define TMC_OFF  524288L                          // B*M*C bf16        (67 MB)   K: [b][m][c]
#define TCM_OFF  67633152L                        // B*272*M bf16      (71.3 MB) V: [b][row][m]
#define SNC_OFF  138936320L                       // B*N*C bf16        (1 MB)    Q^T: [b][n][c]
#define PART_OFF 139984896L                       // B*16*N*272 bf16   (17.8 MB)
#define ZP_OFF   157810688L                       // B*16*N f32
#define PP_OFF   157941760L                       // B*16*N f32  (end 158072832)
// stats partials live in the part region (used before k_main writes part)
#define PS_OFF   PART_OFF                         // [B][4][M] f32 sums   (2 MB)
#define PS2_OFF  (PART_OFF + 2097152L)            // [B][4][M] f32 sumsq  (2 MB)

// output float offsets
#define O_COORD 0L
#define O_W     6144L
#define O_DESC  8192L
#define O_P2D   532480L
#define O_VALID 536576L
#define O_MAXSM 538624L

using f32x4 = __attribute__((ext_vector_type(4))) float;
using s16x8 = __attribute__((ext_vector_type(8))) short;

__device__ inline unsigned short f2bf(float x) {
    union { float f; unsigned int u; } v; v.f = x;
    unsigned int r = v.u + 0x7FFFu + ((v.u >> 16) & 1u);   // RNE
    return (unsigned short)(r >> 16);
}
__device__ inline float bf2f(unsigned short u) {
    union { unsigned int u; float f; } v; v.u = ((unsigned int)u) << 16;
    return v.f;
}
__device__ inline float exp2v(float x) {
    float r; asm("v_exp_f32 %0, %1" : "=v"(r) : "v"(x)); return r;
}
__device__ inline unsigned int cvtpk(float lo, float hi) {
    unsigned int r;
    asm("v_cvt_pk_bf16_f32 %0, %1, %2" : "=v"(r) : "v"(lo), "v"(hi));
    return r;
}

__device__ inline void gld_lds16(const unsigned short* g, unsigned short* l) {
    __builtin_amdgcn_global_load_lds(
        (const __attribute__((address_space(1))) unsigned int*)g,
        (__attribute__((address_space(3))) unsigned int*)l, 16, 0, 0);
}

// ------- prep A: tgt_desc f32 -> tmc bf16 [b][m][c] + tcm bf16 [b][c][m],
//                 plus per-(c-block, m) partial sums for the column stats -------
__global__ void k_prep_tgt(const float* __restrict__ tgt,
                           unsigned short* __restrict__ tmc,
                           unsigned short* __restrict__ tcm,
                           float* __restrict__ ps,
                           float* __restrict__ ps2) {
    __shared__ float lds[64][65];
    __shared__ float sm[4][64], sm2[4][64];
    int b = blockIdx.z, cy = blockIdx.y, c0 = cy * 64;
    long m0 = (long)blockIdx.x * 64;
    int ty = threadIdx.x >> 6, tx = threadIdx.x & 63;
    float s = 0.f, s2 = 0.f;
    #pragma unroll
    for (int k = 0; k < 16; ++k) {
        int ci = 4 * k + ty;
        float v = tgt[((long)b * Cc + c0 + ci) * Mm + m0 + tx];
        lds[ci][tx] = v;
        s += v; s2 += v * v;
        tcm[((long)b * VROWS + c0 + ci) * Mm + m0 + tx] = f2bf(v);
    }
    sm[ty][tx] = s; sm2[ty][tx] = s2;
    __syncthreads();
    #pragma unroll
    for (int k = 0; k < 16; ++k) {
        int mi = 4 * k + ty;
        tmc[((long)b * Mm + m0 + mi) * Cc + c0 + tx] = f2bf(lds[tx][mi]);
    }
    if (ty == 0) {
        long o = ((long)b * 4 + cy) * Mm + m0 + tx;
        ps[o]  = (sm[0][tx] + sm[1][tx]) + (sm[2][tx] + sm[3][tx]);
        ps2[o] = (sm2[0][tx] + sm2[1][tx]) + (sm2[2][tx] + sm2[3][tx]);
    }
}

// ------- prep B: finish stats -> scl; write coords/weights/ones rows of V -------
__global__ void k_stats(const float* __restrict__ ps,
                        const float* __restrict__ ps2,
                        const float* __restrict__ coords,
                        const float* __restrict__ weights,
                        float* __restrict__ scl,
                        unsigned short* __restrict__ tcm) {
    int b = blockIdx.y;
    long m = (long)blockIdx.x * 256 + threadIdx.x;
    float s = 0.f, s2 = 0.f;
    #pragma unroll
    for (int k = 0; k < 4; ++k) {
        long o = ((long)b * 4 + k) * Mm + m;
        s += ps[o]; s2 += ps2[o];
    }
    float var = fmaxf((s2 - s * s * (1.0f / Cc)) * (1.0f / (Cc - 1)), 1e-20f);
    scl[(long)b * Mm + m] = 1.4426950408889634f * rsqrtf(var) * (1.0f / (Cc * 0.01f));
    unsigned short* vrow = tcm + ((long)b * VROWS + 256) * Mm + m;
    #pragma unroll
    for (int i = 0; i < 3; ++i) vrow[(long)i * Mm] = f2bf(coords[((long)b * 3 + i) * Mm + m]);
    vrow[3L * Mm] = f2bf(weights[(long)b * Mm + m]);
    vrow[4L * Mm] = 0x3F80;   // ones row (channel 260): Z comes out of the PV MFMA
    #pragma unroll
    for (int i = 5; i < 16; ++i) vrow[(long)i * Mm] = 0;
}

// ------- prep C: src_desc_norm f32 -> snc bf16 [b][n][c] -------
__global__ void k_prep_src(const float* __restrict__ src, unsigned short* __restrict__ snc) {
    __shared__ float lds[64][65];
    int b = blockIdx.z, c0 = blockIdx.y * 64, n0 = blockIdx.x * 64;
    int ty = threadIdx.x >> 6, tx = threadIdx.x & 63;
    #pragma unroll
    for (int k = 0; k < 16; ++k)
        lds[4 * k + ty][tx] = src[((long)b * Cc + c0 + 4 * k + ty) * Nn + n0 + tx];
    __syncthreads();
    #pragma unroll
    for (int k = 0; k < 16; ++k) {
        int ni = 4 * k + ty;
        snc[((long)b * Nn + n0 + ni) * Cc + c0 + tx] = f2bf(lds[tx][ni]);
    }
}

// ------- main fused kernel: LDS-staged, software-pipelined flash loop -------
// block = 4 waves * 32 n = 128 n; 128 steps of 32 m. Per iteration s:
//   stage(s+1)  [global_load_lds, K dbuf / V tribuf]
//   QK(s)  -> exp -> pack -> pbuf[s&1]          (stream 1)
//   PV(s-1) <- pbuf[(s-1)&1], V tile s-1        (stream 2, independent)
//   one barrier; buffer rotate.
// The two streams overlap: PV MFMAs hide QK's exp/pack VALU and pbuf latency.
__global__ __launch_bounds__(256, 1) void k_main(const unsigned short* __restrict__ tmc,
                                                 const unsigned short* __restrict__ tcm,
                                                 const unsigned short* __restrict__ snc,
                                                 const float* __restrict__ scl,
                                                 unsigned short* __restrict__ part,
                                                 float* __restrict__ zp,
                                                 float* __restrict__ pp) {
    __shared__ __align__(16) unsigned short kb0[8192], kb1[8192];             // 16 KB x2
    __shared__ __align__(16) unsigned short vb0[8704], vb1[8704], vb2[8704];  // 17 KB x3
    __shared__ __align__(16) unsigned short pbuf[2][4][2][16][56];            // 28.7 KB

    int w = threadIdx.x >> 6, lane = threadIdx.x & 63;
    int l15 = lane & 15, lg = lane >> 4;
    int b = blockIdx.z, nt = blockIdx.y, mc = blockIdx.x;
    int nb = nt * 128 + w * 32;
    long mbase = (long)mc * MCHUNK;

    // Q^T B-fragments for 2 n-subtiles
    s16x8 qf[2][8];
    #pragma unroll
    for (int st = 0; st < 2; ++st) {
        const unsigned short* qp = snc + ((long)b * Nn + nb + st * 16 + l15) * Cc + lg * 8;
        #pragma unroll
        for (int cc = 0; cc < 8; ++cc) qf[st][cc] = *(const s16x8*)(qp + cc * 32);
    }

    f32x4 acc[2][17];
    #pragma unroll
    for (int st = 0; st < 2; ++st)
        #pragma unroll
        for (int t = 0; t < 17; ++t) acc[st][t] = (f32x4){0.f, 0.f, 0.f, 0.f};
    float pmax[2] = {0.f, 0.f};

    // ---- staging source pointers (per-lane, pre-swizzled) ----
    const unsigned short* tmcb = tmc + (long)b * Mm * Cc;
    const unsigned short* tcmb = tcm + (long)b * VROWS * (long)Mm;
    const unsigned short* ksrc[4];
    #pragma unroll
    for (int i = 0; i < 4; ++i) {
        int ins = w * 4 + i;
        int row = 2 * ins + (lane >> 5);
        int gs  = (lane & 31) ^ (row & 7);
        ksrc[i] = tmcb + (mbase + row) * Cc + gs * 8;
    }
    const unsigned short* vsrc[5];
    int vj = ((lane & 3) ^ ((lane >> 3) & 3)) * 8;
    #pragma unroll
    for (int i = 0; i < 5; ++i) {
        int ins = (i < 4) ? (w * 4 + i) : 16;
        int row = ins * 16 + (lane >> 2);
        vsrc[i] = tcmb + (long)row * Mm + mbase + vj;
    }

    const float* sclb = scl + (long)b * Mm;

    auto stage = [&](unsigned short* kd, unsigned short* vd) {
        #pragma unroll
        for (int i = 0; i < 4; ++i) gld_lds16(ksrc[i], kd + (w * 4 + i) * 512);
        #pragma unroll
        for (int i = 0; i < 4; ++i) gld_lds16(vsrc[i], vd + (w * 4 + i) * 512);
        if (w == 3) gld_lds16(vsrc[4], vd + 16 * 512);
    };
    auto advance = [&]() {
        #pragma unroll
        for (int i = 0; i < 4; ++i) ksrc[i] += MSTEP * Cc;
        #pragma unroll
        for (int i = 0; i < 5; ++i) vsrc[i] += MSTEP;
    };

    // rotating LDS buffers: tile s lives in kc/vc during its QK, vp during its PV
    unsigned short *kc = kb0, *kn = kb1;
    unsigned short *vp = vb2, *vc = vb0, *vn = vb1;

    stage(kc, vc);      // tile 0
    advance();
    __syncthreads();

    int ksw = (l15 & 7) << 3;              // K read swizzle (elements)
    int vsw = (lg ^ ((l15 >> 1) & 3)) * 8; // V read chunk swizzle (elements)

    // software-pipelined scl (registers one iteration ahead)
    float4 scA = *(const float4*)(sclb + mbase + lg * 4);
    float4 scB = *(const float4*)(sclb + mbase + 16 + lg * 4);

    for (int s = 0; s < NIT; ++s) {
        if (s + 1 < NIT) { stage(kn, vn); advance(); }
        int sn = (s + 1 < NIT) ? s + 1 : s;
        float4 nA = *(const float4*)(sclb + mbase + (long)sn * MSTEP + lg * 4);
        float4 nB = *(const float4*)(sclb + mbase + (long)sn * MSTEP + 16 + lg * 4);

        // ---- stream 1: QK(s) -> pbuf[s&1] ----
        unsigned short* pw = &pbuf[s & 1][w][0][0][0];
        #pragma unroll
        for (int t = 0; t < 2; ++t) {
            f32x4 dA = (f32x4){0.f, 0.f, 0.f, 0.f};
            f32x4 dB = (f32x4){0.f, 0.f, 0.f, 0.f};
            const unsigned short* kr = kc + (t * 16 + l15) * Cc;
            #pragma unroll
            for (int cc = 0; cc < 8; ++cc) {
                s16x8 kf = *(const s16x8*)(kr + ((cc * 32 + lg * 8) ^ ksw));
                dA = __builtin_amdgcn_mfma_f32_16x16x32_bf16(kf, qf[0][cc], dA, 0, 0, 0);
                dB = __builtin_amdgcn_mfma_f32_16x16x32_bf16(kf, qf[1][cc], dB, 0, 0, 0);
            }
            float4 sc = t ? scB : scA;
            #pragma unroll
            for (int st = 0; st < 2; ++st) {
                f32x4 d = st ? dB : dA;
                float p0 = exp2v(d.x * sc.x);
                float p1 = exp2v(d.y * sc.y);
                float p2 = exp2v(d.z * sc.z);
                float p3 = exp2v(d.w * sc.w);
                pmax[st] = fmaxf(pmax[st], fmaxf(fmaxf(p0, p1), fmaxf(p2, p3)));
                unsigned long long pk =
                    (unsigned long long)cvtpk(p0, p1) | ((unsigned long long)cvtpk(p2, p3) << 32);
                *(unsigned long long*)(pw + (st * 16 + l15) * 56 + t * 16 + lg * 4) = pk;
            }
        }

        // ---- stream 2: PV(s-1) <- pbuf[(s-1)&1], V tile in vp ----
        if (s) {
            const unsigned short* pr = &pbuf[(s & 1) ^ 1][w][0][0][0];
            s16x8 pfA = *(const s16x8*)(pr + l15 * 56 + lg * 8);
            s16x8 pfB = *(const s16x8*)(pr + (16 + l15) * 56 + lg * 8);
            #pragma unroll
            for (int t = 0; t < 17; ++t) {
                s16x8 vf = *(const s16x8*)(vp + (t * 16 + l15) * MSTEP + vsw);
                acc[0][t] = __builtin_amdgcn_mfma_f32_16x16x32_bf16(vf, pfA, acc[0][t], 0, 0, 0);
                acc[1][t] = __builtin_amdgcn_mfma_f32_16x16x32_bf16(vf, pfB, acc[1][t], 0, 0, 0);
            }
        }

        scA = nA; scB = nB;
        __syncthreads();
        // rotate buffers
        unsigned short* kt = kc; kc = kn; kn = kt;
        unsigned short* vt = vp; vp = vc; vc = vn; vn = vt;
    }

    // ---- tail: PV(NIT-1) ----
    {
        const unsigned short* pr = &pbuf[(NIT - 1) & 1][w][0][0][0];
        s16x8 pfA = *(const s16x8*)(pr + l15 * 56 + lg * 8);
        s16x8 pfB = *(const s16x8*)(pr + (16 + l15) * 56 + lg * 8);
        #pragma unroll
        for (int t = 0; t < 17; ++t) {
            s16x8 vf = *(const s16x8*)(vp + (t * 16 + l15) * MSTEP + vsw);
            acc[0][t] = __builtin_amdgcn_mfma_f32_16x16x32_bf16(vf, pfA, acc[0][t], 0, 0, 0);
            acc[1][t] = __builtin_amdgcn_mfma_f32_16x16x32_bf16(vf, pfB, acc[1][t], 0, 0, 0);
        }
    }

    // Z sits in acc[st][16].x on lanes lg==1 (channel 260 = ones row)
    #pragma unroll
    for (int st = 0; st < 2; ++st) {
        float pt = fmaxf(pmax[st], __shfl_xor(pmax[st], 16));
        pt = fmaxf(pt, __shfl_xor(pt, 32));
        long zi = ((long)(b * MCn + mc)) * Nn + nb + st * 16;
        if (lg == 1) zp[zi + l15] = acc[st][16].x;
        if (lane < 16) pp[zi + lane] = pt;
        unsigned short* po = part + (((long)(b * MCn + mc) * Nn) + nb + st * 16 + l15) * VROWS;
        #pragma unroll
        for (int t = 0; t < 17; ++t) {
            f32x4 a = acc[st][t];
            unsigned long long pk =
                (unsigned long long)cvtpk(a.x, a.y) | ((unsigned long long)cvtpk(a.z, a.w) << 32);
            *(unsigned long long*)&po[t * 16 + lg * 4] = pk;
        }
    }
}

// ------- epilogue: combine m-chunks, normalize, zn(descs), 2D projection, max_softmax -------
__global__ void k_epi(const unsigned short* __restrict__ part,
                      const float* __restrict__ zp,
                      const float* __restrict__ pp,
                      float* __restrict__ out) {
    int w = threadIdx.x >> 6, lane = threadIdx.x & 63;
    int bn = blockIdx.x * 4 + w;
    int b = bn >> 10, n = bn & 1023;

    float Z = 0.f, pm = 0.f;
    #pragma unroll
    for (int mc = 0; mc < MCn; ++mc) {
        long zi = ((long)(b * MCn + mc)) * Nn + n;
        Z += zp[zi];
        pm = fmaxf(pm, pp[zi]);
    }
    float invZ = 1.0f / Z;

    float dv[4], s1 = 0.f, s2 = 0.f;
    #pragma unroll
    for (int k = 0; k < 4; ++k) {
        int c = lane + 64 * k;
        float s = 0.f;
        #pragma unroll
        for (int mc = 0; mc < MCn; ++mc)
            s += bf2f(part[((long)(b * MCn + mc) * Nn + n) * VROWS + c]);
        float d = s * invZ;
        dv[k] = d; s1 += d; s2 += d * d;
    }
    #pragma unroll
    for (int off = 1; off < 64; off <<= 1) { s1 += __shfl_xor(s1, off); s2 += __shfl_xor(s2, off); }
    float mean = s1 * (1.0f / 256.0f);
    float var = fmaxf((s2 - 256.0f * mean * mean) * (1.0f / 255.0f), 1e-20f);
    float istd = 1.0f / sqrtf(var);
    #pragma unroll
    for (int k = 0; k < 4; ++k)
        out[O_DESC + ((long)b * Cc + lane + 64 * k) * Nn + n] = (dv[k] - mean) * istd;

    float ex = 0.f;
    if (lane < 4) {
        int c = 256 + lane;
        #pragma unroll
        for (int mc = 0; mc < MCn; ++mc)
            ex += bf2f(part[((long)(b * MCn + mc) * Nn + n) * VROWS + c]);
        ex *= invZ;
    }
    float pc0 = __shfl(ex, 0), pc1 = __shfl(ex, 1), pc2 = __shfl(ex, 2), wv = __shfl(ex, 3);
    if (lane == 0) {
        out[O_COORD + ((long)b * 3 + 0) * Nn + n] = pc0;
        out[O_COORD + ((long)b * 3 + 1) * Nn + n] = pc1;
        out[O_COORD + ((long)b * 3 + 2) * Nn + n] = pc2;
        out[O_W + (long)b * Nn + n] = wv;
        const float cmin = 33.048f;                 // (256/2 - 0.5) * 0.2592
        out[O_P2D + ((long)b * Nn + n) * 2 + 0] = (cmin + pc1) * (1.0f / 0.2592f);
        out[O_P2D + ((long)b * Nn + n) * 2 + 1] = (cmin - pc0) * (1.0f / 0.2592f);
        out[O_VALID + (long)b * Nn + n] = 1.0f;
        atomicMax((unsigned int*)out + O_MAXSM + b, __float_as_uint(pm * invZ));
    }
}

extern "C" void kernel_launch(void* const* d_in, const int* in_sizes, int n_in,
                              void* d_out, int out_size, void* d_ws, size_t ws_size,
                              hipStream_t stream) {
    const float* tgt_coords  = (const float*)d_in[1];
    const float* tgt_weights = (const float*)d_in[3];
    const float* src_desc    = (const float*)d_in[5];
    const float* tgt_desc    = (const float*)d_in[6];

    char* ws = (char*)d_ws;
    float* scl           = (float*)(ws + SCL_OFF);
    unsigned short* tmc  = (unsigned short*)(ws + TMC_OFF);
    unsigned short* tcm  = (unsigned short*)(ws + TCM_OFF);
    unsigned short* snc  = (unsigned short*)(ws + SNC_OFF);
    unsigned short* part = (unsigned short*)(ws + PART_OFF);
    float* ps            = (float*)(ws + PS_OFF);
    float* ps2           = (float*)(ws + PS2_OFF);
    float* zp            = (float*)(ws + ZP_OFF);
    float* pp            = (float*)(ws + PP_OFF);
    float* out           = (float*)d_out;

    k_prep_tgt<<<dim3(Mm / 64, Cc / 64, Bb), 256, 0, stream>>>(tgt_desc, tmc, tcm, ps, ps2);
    k_stats<<<dim3(Mm / 256, Bb), 256, 0, stream>>>(ps, ps2, tgt_coords, tgt_weights, scl, tcm);
    k_prep_src<<<dim3(Nn / 64, Cc / 64, Bb), 256, 0, stream>>>(src_desc, snc);
    k_main<<<dim3(MCn, Nn / 128, Bb), 256, 0, stream>>>(tmc, tcm, snc, scl, part, zp, pp);
    hipMemsetAsync((char*)d_out + O_MAXSM * 4, 0, 2 * sizeof(float), stream);
    k_epi<<<dim3((Bb * Nn) / 4), 256, 0, stream>>>(part, zp, pp, out);
}